// Round 3
// baseline (558.651 us; speedup 1.0000x reference)
//
#include <hip/hip_runtime.h>

#define T_TOKENS 4096
#define HIDDEN   2048
#define INTERM   768
#define NE       8
#define NPAIR    8192   // T_TOKENS * TOP_K
#define NROT     4
#define MAXT     72     // max total m-tiles across experts

typedef __bf16 bf16x8 __attribute__((ext_vector_type(8)));
typedef float  f32x4  __attribute__((ext_vector_type(4)));

__device__ __forceinline__ unsigned short f2bf(float f) {
  unsigned u = __float_as_uint(f);
  u += 0x7fffu + ((u >> 16) & 1u);   // round-to-nearest-even (finite inputs only)
  return (unsigned short)(u >> 16);
}

__device__ __forceinline__ void async16(const void* g, void* l) {
  __builtin_amdgcn_global_load_lds((const __attribute__((address_space(1))) void*)g,
                                   (__attribute__((address_space(3))) void*)l, 16, 0, 0);
}

// ---------------- routing: histogram / scan+tilemap / scatter ----------------
__global__ void k_hist(const int* __restrict__ idx, int* __restrict__ cnt) {
  const int t = blockIdx.x * 256 + threadIdx.x;
  if (t < NPAIR) atomicAdd(&cnt[idx[t]], 1);
}

__global__ void k_scan(const int* __restrict__ cnt, int* __restrict__ off,
                       int* __restrict__ cur, int* __restrict__ tmap,
                       int* __restrict__ nv) {
  if (threadIdx.x == 0) {
    int a = 0, tt = 0;
    for (int e = 0; e < NE; ++e) {
      off[e] = a; cur[e] = 0;
      const int c = cnt[e];
      for (int m = 0; m < c; m += 128) tmap[tt++] = (e << 16) | (m >> 7);
      a += c;
    }
    nv[0] = tt;                      // number of VALID m-tiles
    for (; tt < MAXT; ++tt) tmap[tt] = -1;
  }
}

// pt[pos] = ORIGINAL pair index t (token = t>>1, slot = t&1)
__global__ void k_scatter(const int* __restrict__ idx, const float* __restrict__ wts,
                          const int* __restrict__ off, int* __restrict__ cur,
                          int* __restrict__ pt, float* __restrict__ pw) {
  const int t = blockIdx.x * 256 + threadIdx.x;
  if (t < NPAIR) {
    const int e = idx[t];
    const int pos = off[e] + atomicAdd(&cur[e], 1);
    pt[pos] = t;          // pair id (carries token and slot)
    pw[pos] = wts[t];     // routing weight
  }
}

// ---------------- build per-destination rotation tables + recip channel scales ----
// entry (group g, rot r, dest d): {cos, signed_sin, partner, 0};
// forward: new[d] = cos*old[d] + signed_sin*old[partner]
__global__ void k_tbl(const int* __restrict__ gp, const float* __restrict__ ga,
                      const int* __restrict__ dp, const float* __restrict__ da,
                      const float* __restrict__ gch, const float* __restrict__ dch,
                      float4* __restrict__ tg, float4* __restrict__ td,
                      float* __restrict__ grch, float* __restrict__ drch) {
  const int t = blockIdx.x * 256 + threadIdx.x;
  if (t < NROT * (HIDDEN / 2)) {
    const int r = t >> 10, s = t & 1023;          // slot s over 1024 pairs
    const int grp = s >> 6;
    const int i = gp[r * HIDDEN + 2 * s], j = gp[r * HIDDEN + 2 * s + 1];
    const float a = ga[r * (HIDDEN / 2) + s];
    const float c = cosf(a), sn = sinf(a);
    tg[(grp * NROT + r) * 128 + i] = make_float4(c, -sn, __int_as_float(j), 0.f);
    tg[(grp * NROT + r) * 128 + j] = make_float4(c,  sn, __int_as_float(i), 0.f);
  }
  if (t < NROT * (INTERM / 2)) {
    const int r = t / (INTERM / 2), s = t - r * (INTERM / 2);
    const int grp = s >> 6;
    const int i = dp[r * INTERM + 2 * s], j = dp[r * INTERM + 2 * s + 1];
    const float a = da[r * (INTERM / 2) + s];
    const float c = cosf(a), sn = sinf(a);
    td[(grp * NROT + r) * 128 + i] = make_float4(c, -sn, __int_as_float(j), 0.f);
    td[(grp * NROT + r) * 128 + j] = make_float4(c,  sn, __int_as_float(i), 0.f);
  }
  if (t < HIDDEN) grch[t] = 1.0f / gch[t];
  if (t < INTERM) drch[t] = 1.0f / dch[t];
}

// helper: 4 forward rotation passes on (v0,v1) held across the wave (128-group)
#define FWD_ROT(tl, v0, v1)                                                     \
  _Pragma("unroll")                                                             \
  for (int r = 0; r < NROT; ++r) {                                              \
    const float4 e0 = tl[r * 128 + l];                                          \
    const float4 e1 = tl[r * 128 + 64 + l];                                     \
    const int p0 = __float_as_int(e0.z), p1 = __float_as_int(e1.z);             \
    const int a0 = (p0 & 63) << 2, a1 = (p1 & 63) << 2;                         \
    _Pragma("unroll")                                                           \
    for (int q = 0; q < 4; ++q) {                                               \
      const int x0 = __float_as_int(v0[q]), x1 = __float_as_int(v1[q]);         \
      const float lo0 = __int_as_float(__builtin_amdgcn_ds_bpermute(a0, x0));   \
      const float hi0 = __int_as_float(__builtin_amdgcn_ds_bpermute(a0, x1));   \
      const float lo1 = __int_as_float(__builtin_amdgcn_ds_bpermute(a1, x0));   \
      const float hi1 = __int_as_float(__builtin_amdgcn_ds_bpermute(a1, x1));   \
      const float op0 = (p0 & 64) ? hi0 : lo0;                                  \
      const float op1 = (p1 & 64) ? hi1 : lo1;                                  \
      {                                                                         \
        _Pragma("clang fp contract(off)")                                       \
        v0[q] = e0.x * v0[q] + e0.y * op0;                                      \
        v1[q] = e1.x * v1[q] + e1.y * op1;                                      \
      }                                                                         \
    }                                                                           \
  }

// ---------------- weight pseudo-quantize (forward only, outputs rotated q) ------
__global__ __launch_bounds__(256) void k_quant(
    const float* __restrict__ W, const float4* __restrict__ tbl,
    const float* __restrict__ ch, unsigned short* __restrict__ out, int In, int G) {
  __shared__ float4 tl[NROT * 128];
  const int wv = threadIdx.x >> 6, l = threadIdx.x & 63;
  const int g = blockIdx.x % G;
  const int rowblk = blockIdx.x / G;
  const int row0 = rowblk * 16 + wv * 4;
  const int colbase = g << 7;
  tl[threadIdx.x]       = tbl[(size_t)g * NROT * 128 + threadIdx.x];
  tl[256 + threadIdx.x] = tbl[(size_t)g * NROT * 128 + 256 + threadIdx.x];
  __syncthreads();
  const float c0 = ch[colbase + l], c1 = ch[colbase + 64 + l];
  float v0[4], v1[4];
#pragma unroll
  for (int q = 0; q < 4; ++q) {
#pragma clang fp contract(off)
    const float* Wr = W + (size_t)(row0 + q) * In + colbase;
    v0[q] = Wr[l] * c0;
    v1[q] = Wr[64 + l] * c1;
  }
  FWD_ROT(tl, v0, v1)
  // fake quant per row; output stays in rotated space
#pragma unroll
  for (int q = 0; q < 4; ++q) {
    float mn = fminf(v0[q], v1[q]), mx = fmaxf(v0[q], v1[q]);
#pragma unroll
    for (int o = 32; o > 0; o >>= 1) {
      mn = fminf(mn, __shfl_xor(mn, o));
      mx = fmaxf(mx, __shfl_xor(mx, o));
    }
    {
#pragma clang fp contract(off)
      const float scale = fmaxf(mx - mn, 1e-5f) / 15.0f;
      const float zero = rintf(-mn / scale);
      const float q0 = fminf(fmaxf(rintf(v0[q] / scale) + zero, 0.0f), 15.0f);
      const float q1 = fminf(fmaxf(rintf(v1[q] / scale) + zero, 0.0f), 15.0f);
      v0[q] = (q0 - zero) * scale;
      v1[q] = (q1 - zero) * scale;
    }
  }
#pragma unroll
  for (int q = 0; q < 4; ++q) {
    unsigned short* Or = out + (size_t)(row0 + q) * In + colbase;
    Or[l]      = f2bf(v0[q]);
    Or[64 + l] = f2bf(v1[q]);
  }
}

// ---------------- x' = R(x / ch) -> bf16 ----------------
__global__ __launch_bounds__(256) void k_rotx(
    const float* __restrict__ X, const float* __restrict__ rch,
    const float4* __restrict__ tbl, unsigned short* __restrict__ out) {
  __shared__ float4 tl[NROT * 128];
  const int wv = threadIdx.x >> 6, l = threadIdx.x & 63;
  const int g = blockIdx.x % 16;                 // HIDDEN/128 groups
  const int rowblk = blockIdx.x / 16;
  const int row0 = rowblk * 16 + wv * 4;
  const int colbase = g << 7;
  tl[threadIdx.x]       = tbl[(size_t)g * NROT * 128 + threadIdx.x];
  tl[256 + threadIdx.x] = tbl[(size_t)g * NROT * 128 + 256 + threadIdx.x];
  __syncthreads();
  const float i0 = rch[colbase + l], i1 = rch[colbase + 64 + l];
  float v0[4], v1[4];
#pragma unroll
  for (int q = 0; q < 4; ++q) {
    const float* Xr = X + (size_t)(row0 + q) * HIDDEN + colbase;
    v0[q] = Xr[l] * i0;
    v1[q] = Xr[64 + l] * i1;
  }
  FWD_ROT(tl, v0, v1)
#pragma unroll
  for (int q = 0; q < 4; ++q) {
    unsigned short* Or = out + (size_t)(row0 + q) * HIDDEN + colbase;
    Or[l]      = f2bf(v0[q]);
    Or[64 + l] = f2bf(v1[q]);
  }
}

// ---------------- inter' = R_d( silu(gate)*up*wgt / ch_d ) -> bf16 ----------------
__global__ __launch_bounds__(256) void k_silu2(
    const float* __restrict__ h, const float* __restrict__ pw,
    const float* __restrict__ rch, const float4* __restrict__ tbl,
    unsigned short* __restrict__ out) {
  __shared__ float4 tl[NROT * 128];
  const int wv = threadIdx.x >> 6, l = threadIdx.x & 63;
  const int g = blockIdx.x % 6;                  // INTERM/128 groups
  const int rowblk = blockIdx.x / 6;
  const int row0 = rowblk * 16 + wv * 4;
  const int colbase = g << 7;
  tl[threadIdx.x]       = tbl[(size_t)g * NROT * 128 + threadIdx.x];
  tl[256 + threadIdx.x] = tbl[(size_t)g * NROT * 128 + 256 + threadIdx.x];
  __syncthreads();
  const float i0 = rch[colbase + l], i1 = rch[colbase + 64 + l];
  float v0[4], v1[4];
#pragma unroll
  for (int q = 0; q < 4; ++q) {
    const int row = row0 + q;
    const float wgt = pw[row];
    const float* hr = h + (size_t)row * 1536 + colbase;
    const float g0 = hr[l], g1 = hr[64 + l];
    const float u0 = hr[768 + l], u1 = hr[768 + 64 + l];
    v0[q] = g0 / (1.0f + expf(-g0)) * u0 * wgt * i0;
    v1[q] = g1 / (1.0f + expf(-g1)) * u1 * wgt * i1;
  }
  FWD_ROT(tl, v0, v1)
#pragma unroll
  for (int q = 0; q < 4; ++q) {
    unsigned short* Or = out + (size_t)(row0 + q) * INTERM + colbase;
    Or[l]      = f2bf(v0[q]);
    Or[64 + l] = f2bf(v1[q]);
  }
}

// ---------------- expert-segmented GEMM: C = A * B^T ----------------
// 3-buffer LDS pipeline, prefetch depth 2, counted vmcnt (T4) + raw s_barrier.
// Safety: each wave waits vmcnt for ITS tile-t loads BEFORE the barrier, so after
// the barrier all waves' tile-t data is resident; stage of tile t+2 is issued
// AFTER the barrier (all step t-1 ds_reads drained via explicit lgkmcnt(0)
// pre-barrier). sched_barrier(0) pins loads/reads from crossing the barrier.
// MODE 0: gather A rows by token (pt>>1), plain store to segment-ordered C.
// MODE 1: A rows are segment-ordered, plain store to pair-indexed C (NO atomics).
template <int MODE>
__launch_bounds__(256, 3)
__global__ void k_gemm(const unsigned short* __restrict__ A,
                       const unsigned short* __restrict__ Bw,
                       float* __restrict__ C,
                       const int* __restrict__ pt,
                       const int* __restrict__ off,
                       const int* __restrict__ cnt,
                       const int* __restrict__ tmap,
                       const int* __restrict__ nv) {
  constexpr int K = MODE ? INTERM : HIDDEN;
  constexpr int N = MODE ? HIDDEN : 2 * INTERM;
  constexpr int XW = MODE ? 16 : 12;            // grid.x

  const int hw  = blockIdx.x + XW * blockIdx.y;
  const int xcd = hw & 7;
  const int pos = hw >> 3;
  const int nvalid = nv[0];
  const int q8 = nvalid >> 3, r8 = nvalid & 7;
  const int rs = q8 + (xcd < r8 ? 1 : 0);       // valid rows for this XCD
  const int y0 = xcd * q8 + (xcd < r8 ? xcd : r8);
  if (pos >= rs * XW) return;
  int xg, yg;
  if (MODE == 1) {                               // B set = 16*192KB = 3MB fits L2
    xg = pos & 15; yg = y0 + (pos >> 4);
  } else {                                       // two halves of 6 n-blocks (3MB)
    const int cap6 = rs * 6;
    const int half = (pos >= cap6) ? 1 : 0;
    const int rem  = pos - half * cap6;
    xg = half * 6 + rem % 6;
    yg = y0 + rem / 6;
  }
  const int tm = tmap[yg];
  if (tm < 0) return;
  const int e = tm >> 16;
  const int m0 = (tm & 0xffff) << 7;
  const int count = cnt[e];
  const int seg = off[e];
  const int n0 = xg * 128;
  const unsigned short* Be = Bw + (size_t)e * N * K;

  __shared__ unsigned short As[3][128 * 32];
  __shared__ unsigned short Bs[3][128 * 32];

  const int tid = threadIdx.x;
  const int w = tid >> 6;
  const int l = tid & 63;
  const int r0 = w * 16 + (l >> 2);
  const int r1 = r0 + 64;
  const int kco = (l & 3) * 8;

  int p0 = m0 + r0; if (p0 > count - 1) p0 = count - 1;
  int p1 = m0 + r1; if (p1 > count - 1) p1 = count - 1;
  size_t arow0, arow1;
  if (MODE == 0) { arow0 = (size_t)(pt[seg + p0] >> 1); arow1 = (size_t)(pt[seg + p1] >> 1); }
  else           { arow0 = (size_t)(seg + p0); arow1 = (size_t)(seg + p1); }
  const unsigned short* pa0 = A + arow0 * K + kco;
  const unsigned short* pa1 = A + arow1 * K + kco;
  const unsigned short* pb0 = Be + (size_t)(n0 + r0) * K + kco;
  const unsigned short* pb1 = Be + (size_t)(n0 + r1) * K + kco;

  const int ko = (l >> 4) * 8;
  const int mrow = (w & 1) * 64 + (l & 15);
  const int nrow = (w >> 1) * 64 + (l & 15);

  f32x4 acc[4][4];
#pragma unroll
  for (int i = 0; i < 4; ++i)
#pragma unroll
    for (int j = 0; j < 4; ++j) acc[i][j] = (f32x4)0.0f;

#define STAGE(b, kn) do {                              \
    async16(pa0 + (kn), &As[b][w * 512]);              \
    async16(pa1 + (kn), &As[b][(w + 4) * 512]);        \
    async16(pb0 + (kn), &Bs[b][w * 512]);              \
    async16(pb1 + (kn), &Bs[b][(w + 4) * 512]);        \
  } while (0)

  STAGE(0, 0);          // tile 0 -> buf 0   (4 vmem ops/wave)
  STAGE(1, 32);         // tile 1 -> buf 1   (8 outstanding)

  int buf = 0;
  for (int k0 = 0; k0 < K; k0 += 32) {
    // all our ds_reads of the previous step done (buffer about to be re-staged)
    asm volatile("s_waitcnt lgkmcnt(0)" ::: "memory");
    // our 4 loads of the CURRENT tile landed; keep next tile's 4 in flight.
    // Last step: only 4 outstanding, so a counted 4 would not wait -> use 0.
    if (k0 + 32 < K) asm volatile("s_waitcnt vmcnt(4)" ::: "memory");
    else             asm volatile("s_waitcnt vmcnt(0)" ::: "memory");
    __builtin_amdgcn_s_barrier();              // now everyone's tile data resident
    __builtin_amdgcn_sched_barrier(0);         // pin: nothing crosses the barrier
    const int kn = k0 + 64;
    if (kn < K) {
      const int nb3 = (buf == 0) ? 2 : buf - 1;   // (buf+2)%3
      STAGE(nb3, kn);                             // overwrites buffer read at t-1
    }
    bf16x8 af[4], bfr[4];
#pragma unroll
    for (int i = 0; i < 4; ++i)
      af[i] = *(const bf16x8*)&As[buf][(mrow + i * 16) * 32 + ko];
#pragma unroll
    for (int j = 0; j < 4; ++j)
      bfr[j] = *(const bf16x8*)&Bs[buf][(nrow + j * 16) * 32 + ko];
#pragma unroll
    for (int i = 0; i < 4; ++i)
#pragma unroll
      for (int j = 0; j < 4; ++j)
        acc[i][j] = __builtin_amdgcn_mfma_f32_16x16x32_bf16(af[i], bfr[j], acc[i][j], 0, 0, 0);
    buf = (buf == 2) ? 0 : buf + 1;
  }
#undef STAGE

  const int mb = (w & 1) * 64 + (l >> 4) * 4;
  const int nb = n0 + (w >> 1) * 64 + (l & 15);
#pragma unroll
  for (int i = 0; i < 4; ++i) {
#pragma unroll
    for (int j = 0; j < 4; ++j) {
#pragma unroll
      for (int r = 0; r < 4; ++r) {
        const int mm = m0 + mb + i * 16 + r;
        if (mm < count) {
          const int nn = nb + j * 16;
          if (MODE == 0) {
            C[(size_t)(seg + mm) * N + nn] = acc[i][j][r];
          } else {
            // pair-indexed row: ybuf[pair][HIDDEN], plain store
            C[(size_t)pt[seg + mm] * N + nn] = acc[i][j][r];
          }
        }
      }
    }
  }
}

// ---------------- out[t] = ybuf[2t] + ybuf[2t+1] ----------------
__global__ __launch_bounds__(256) void k_combine(const float4* __restrict__ y,
                                                 float4* __restrict__ out) {
  const int t = blockIdx.x;                       // token
  const float4* y0 = y + (size_t)(2 * t) * (HIDDEN / 4);
  const float4* y1 = y + (size_t)(2 * t + 1) * (HIDDEN / 4);
  float4* o = out + (size_t)t * (HIDDEN / 4);
#pragma unroll
  for (int q = 0; q < 2; ++q) {
    const int c = threadIdx.x + q * 256;          // 512 float4 per token
    const float4 a = y0[c], b = y1[c];
    o[c] = make_float4(a.x + b.x, a.y + b.y, a.z + b.z, a.w + b.w);
  }
}

// ---------------- launch ----------------
extern "C" void kernel_launch(void* const* d_in, const int* in_sizes, int n_in,
                              void* d_out, int out_size, void* d_ws, size_t ws_size,
                              hipStream_t stream) {
  const float* hs  = (const float*)d_in[0];
  const int*   tki = (const int*)d_in[1];
  const float* tkw = (const float*)d_in[2];
  const float* guw = (const float*)d_in[3];
  const float* dww = (const float*)d_in[4];
  const int*   gupr= (const int*)d_in[5];
  const float* gua = (const float*)d_in[6];
  const int*   dwp = (const int*)d_in[7];
  const float* dwa = (const float*)d_in[8];
  const float* gus = (const float*)d_in[9];
  const float* dwsc= (const float*)d_in[10];
  float* out = (float*)d_out;
  char* ws = (char*)d_ws;

  unsigned short* gup_bf = (unsigned short*)(ws + 0);          //  50,331,648 B
  unsigned short* dwn_bf = (unsigned short*)(ws + 50331648);   //  25,165,824 B
  unsigned short* x_bf   = (unsigned short*)(ws + 75497472);   //  16,777,216 B
  float*          hbuf   = (float*)(ws + 92274688);            //  50,331,648 B
  unsigned short* interb = (unsigned short*)(ws + 142606336);  //  12,582,912 B
  // ybuf (8192 x 2048 f32 = 67,108,864 B) reuses x_bf + hbuf (both dead after k_silu2)
  float*          ybuf   = (float*)(ws + 75497472);
  int*            pt     = (int*)(ws + 155189248);             //  32,768 B
  float*          pw     = (float*)(ws + 155222016);           //  32,768 B
  int*            cnt    = (int*)(ws + 155254784);             //  cnt/off/cur/tmap/nv (<4 KiB)
  int*            off    = cnt + 8;
  int*            cur    = cnt + 16;
  int*            tmap   = cnt + 24;
  int*            nv     = cnt + 120;
  float4*         tg     = (float4*)(ws + 155258880);          // 131,072 B (16 grp)
  float4*         td     = (float4*)(ws + 155389952);          //  49,152 B (6 grp)
  float*          grch   = (float*)(ws + 155439104);           //   8,192 B
  float*          drch   = (float*)(ws + 155447296);           //   3,072 B

  (void)hipMemsetAsync(cnt, 0, 32, stream);

  k_hist<<<32, 256, 0, stream>>>(tki, cnt);
  k_scan<<<1, 64, 0, stream>>>(cnt, off, cur, tmap, nv);
  k_scatter<<<32, 256, 0, stream>>>(tki, tkw, off, cur, pt, pw);
  k_tbl<<<16, 256, 0, stream>>>(gupr, gua, dwp, dwa, gus, dwsc, tg, td, grch, drch);
  k_rotx<<<4096, 256, 0, stream>>>(hs, grch, tg, x_bf);
  k_quant<<<12288, 256, 0, stream>>>(guw, tg, gus, gup_bf, HIDDEN, 16);
  k_quant<<<6144, 256, 0, stream>>>(dww, td, dwsc, dwn_bf, INTERM, 6);
  k_gemm<0><<<dim3(12, MAXT), 256, 0, stream>>>(x_bf, gup_bf, hbuf, pt, off, cnt, tmap, nv);
  k_silu2<<<3072, 256, 0, stream>>>(hbuf, pw, drch, td, interb);
  k_gemm<1><<<dim3(16, MAXT), 256, 0, stream>>>(interb, dwn_bf, ybuf, pt, off, cnt, tmap, nv);
  k_combine<<<T_TOKENS, 256, 0, stream>>>((const float4*)ybuf, (float4*)out);
}

// Round 4
// 548.447 us; speedup vs baseline: 1.0186x; 1.0186x over previous
//
#include <hip/hip_runtime.h>

#define T_TOKENS 4096
#define HIDDEN   2048
#define INTERM   768
#define NE       8
#define NPAIR    8192   // T_TOKENS * TOP_K
#define NROT     4
#define MAXT     40     // max total 256-row m-tiles across experts (32 + 8)

typedef __bf16 bf16x8 __attribute__((ext_vector_type(8)));
typedef float  f32x4  __attribute__((ext_vector_type(4)));

__device__ __forceinline__ unsigned short f2bf(float f) {
  unsigned u = __float_as_uint(f);
  u += 0x7fffu + ((u >> 16) & 1u);   // round-to-nearest-even (finite inputs only)
  return (unsigned short)(u >> 16);
}

__device__ __forceinline__ void async16(const void* g, void* l) {
  __builtin_amdgcn_global_load_lds((const __attribute__((address_space(1))) void*)g,
                                   (__attribute__((address_space(3))) void*)l, 16, 0, 0);
}

// ---------------- routing: histogram / scan+tilemap / scatter ----------------
__global__ void k_hist(const int* __restrict__ idx, int* __restrict__ cnt) {
  const int t = blockIdx.x * 256 + threadIdx.x;
  if (t < NPAIR) atomicAdd(&cnt[idx[t]], 1);
}

__global__ void k_scan(const int* __restrict__ cnt, int* __restrict__ off,
                       int* __restrict__ cur, int* __restrict__ tmap,
                       int* __restrict__ nv) {
  if (threadIdx.x == 0) {
    int a = 0, tt = 0;
    for (int e = 0; e < NE; ++e) {
      off[e] = a; cur[e] = 0;
      const int c = cnt[e];
      for (int m = 0; m < c; m += 256) tmap[tt++] = (e << 16) | (m >> 8);
      a += c;
    }
    nv[0] = tt;                      // number of VALID 256-row m-tiles
    for (; tt < MAXT; ++tt) tmap[tt] = -1;
  }
}

// pt[pos] = ORIGINAL pair index t (token = t>>1, slot = t&1)
__global__ void k_scatter(const int* __restrict__ idx, const float* __restrict__ wts,
                          const int* __restrict__ off, int* __restrict__ cur,
                          int* __restrict__ pt, float* __restrict__ pw) {
  const int t = blockIdx.x * 256 + threadIdx.x;
  if (t < NPAIR) {
    const int e = idx[t];
    const int pos = off[e] + atomicAdd(&cur[e], 1);
    pt[pos] = t;          // pair id (carries token and slot)
    pw[pos] = wts[t];     // routing weight
  }
}

// ---------------- build per-destination rotation tables + recip channel scales ----
// entry (group g, rot r, dest d): {cos, signed_sin, partner, 0};
// forward: new[d] = cos*old[d] + signed_sin*old[partner]
__global__ void k_tbl(const int* __restrict__ gp, const float* __restrict__ ga,
                      const int* __restrict__ dp, const float* __restrict__ da,
                      const float* __restrict__ gch, const float* __restrict__ dch,
                      float4* __restrict__ tg, float4* __restrict__ td,
                      float* __restrict__ grch, float* __restrict__ drch) {
  const int t = blockIdx.x * 256 + threadIdx.x;
  if (t < NROT * (HIDDEN / 2)) {
    const int r = t >> 10, s = t & 1023;          // slot s over 1024 pairs
    const int grp = s >> 6;
    const int i = gp[r * HIDDEN + 2 * s], j = gp[r * HIDDEN + 2 * s + 1];
    const float a = ga[r * (HIDDEN / 2) + s];
    const float c = cosf(a), sn = sinf(a);
    tg[(grp * NROT + r) * 128 + i] = make_float4(c, -sn, __int_as_float(j), 0.f);
    tg[(grp * NROT + r) * 128 + j] = make_float4(c,  sn, __int_as_float(i), 0.f);
  }
  if (t < NROT * (INTERM / 2)) {
    const int r = t / (INTERM / 2), s = t - r * (INTERM / 2);
    const int grp = s >> 6;
    const int i = dp[r * INTERM + 2 * s], j = dp[r * INTERM + 2 * s + 1];
    const float a = da[r * (INTERM / 2) + s];
    const float c = cosf(a), sn = sinf(a);
    td[(grp * NROT + r) * 128 + i] = make_float4(c, -sn, __int_as_float(j), 0.f);
    td[(grp * NROT + r) * 128 + j] = make_float4(c,  sn, __int_as_float(i), 0.f);
  }
  if (t < HIDDEN) grch[t] = 1.0f / gch[t];
  if (t < INTERM) drch[t] = 1.0f / dch[t];
}

// helper: 4 forward rotation passes on (v0,v1) held across the wave (128-group)
#define FWD_ROT(tl, v0, v1)                                                     \
  _Pragma("unroll")                                                             \
  for (int r = 0; r < NROT; ++r) {                                              \
    const float4 e0 = tl[r * 128 + l];                                          \
    const float4 e1 = tl[r * 128 + 64 + l];                                     \
    const int p0 = __float_as_int(e0.z), p1 = __float_as_int(e1.z);             \
    const int a0 = (p0 & 63) << 2, a1 = (p1 & 63) << 2;                         \
    _Pragma("unroll")                                                           \
    for (int q = 0; q < 4; ++q) {                                               \
      const int x0 = __float_as_int(v0[q]), x1 = __float_as_int(v1[q]);         \
      const float lo0 = __int_as_float(__builtin_amdgcn_ds_bpermute(a0, x0));   \
      const float hi0 = __int_as_float(__builtin_amdgcn_ds_bpermute(a0, x1));   \
      const float lo1 = __int_as_float(__builtin_amdgcn_ds_bpermute(a1, x0));   \
      const float hi1 = __int_as_float(__builtin_amdgcn_ds_bpermute(a1, x1));   \
      const float op0 = (p0 & 64) ? hi0 : lo0;                                  \
      const float op1 = (p1 & 64) ? hi1 : lo1;                                  \
      {                                                                         \
        _Pragma("clang fp contract(off)")                                       \
        v0[q] = e0.x * v0[q] + e0.y * op0;                                      \
        v1[q] = e1.x * v1[q] + e1.y * op1;                                      \
      }                                                                         \
    }                                                                           \
  }

// ---------------- weight pseudo-quantize (forward only, outputs rotated q) ------
__global__ __launch_bounds__(256) void k_quant(
    const float* __restrict__ W, const float4* __restrict__ tbl,
    const float* __restrict__ ch, unsigned short* __restrict__ out, int In, int G) {
  __shared__ float4 tl[NROT * 128];
  const int wv = threadIdx.x >> 6, l = threadIdx.x & 63;
  const int g = blockIdx.x % G;
  const int rowblk = blockIdx.x / G;
  const int row0 = rowblk * 16 + wv * 4;
  const int colbase = g << 7;
  tl[threadIdx.x]       = tbl[(size_t)g * NROT * 128 + threadIdx.x];
  tl[256 + threadIdx.x] = tbl[(size_t)g * NROT * 128 + 256 + threadIdx.x];
  __syncthreads();
  const float c0 = ch[colbase + l], c1 = ch[colbase + 64 + l];
  float v0[4], v1[4];
#pragma unroll
  for (int q = 0; q < 4; ++q) {
#pragma clang fp contract(off)
    const float* Wr = W + (size_t)(row0 + q) * In + colbase;
    v0[q] = Wr[l] * c0;
    v1[q] = Wr[64 + l] * c1;
  }
  FWD_ROT(tl, v0, v1)
  // fake quant per row; output stays in rotated space
#pragma unroll
  for (int q = 0; q < 4; ++q) {
    float mn = fminf(v0[q], v1[q]), mx = fmaxf(v0[q], v1[q]);
#pragma unroll
    for (int o = 32; o > 0; o >>= 1) {
      mn = fminf(mn, __shfl_xor(mn, o));
      mx = fmaxf(mx, __shfl_xor(mx, o));
    }
    {
#pragma clang fp contract(off)
      const float scale = fmaxf(mx - mn, 1e-5f) / 15.0f;
      const float zero = rintf(-mn / scale);
      const float q0 = fminf(fmaxf(rintf(v0[q] / scale) + zero, 0.0f), 15.0f);
      const float q1 = fminf(fmaxf(rintf(v1[q] / scale) + zero, 0.0f), 15.0f);
      v0[q] = (q0 - zero) * scale;
      v1[q] = (q1 - zero) * scale;
    }
  }
#pragma unroll
  for (int q = 0; q < 4; ++q) {
    unsigned short* Or = out + (size_t)(row0 + q) * In + colbase;
    Or[l]      = f2bf(v0[q]);
    Or[64 + l] = f2bf(v1[q]);
  }
}

// ---------------- x' = R(x / ch) -> bf16 ----------------
__global__ __launch_bounds__(256) void k_rotx(
    const float* __restrict__ X, const float* __restrict__ rch,
    const float4* __restrict__ tbl, unsigned short* __restrict__ out) {
  __shared__ float4 tl[NROT * 128];
  const int wv = threadIdx.x >> 6, l = threadIdx.x & 63;
  const int g = blockIdx.x % 16;                 // HIDDEN/128 groups
  const int rowblk = blockIdx.x / 16;
  const int row0 = rowblk * 16 + wv * 4;
  const int colbase = g << 7;
  tl[threadIdx.x]       = tbl[(size_t)g * NROT * 128 + threadIdx.x];
  tl[256 + threadIdx.x] = tbl[(size_t)g * NROT * 128 + 256 + threadIdx.x];
  __syncthreads();
  const float i0 = rch[colbase + l], i1 = rch[colbase + 64 + l];
  float v0[4], v1[4];
#pragma unroll
  for (int q = 0; q < 4; ++q) {
    const float* Xr = X + (size_t)(row0 + q) * HIDDEN + colbase;
    v0[q] = Xr[l] * i0;
    v1[q] = Xr[64 + l] * i1;
  }
  FWD_ROT(tl, v0, v1)
#pragma unroll
  for (int q = 0; q < 4; ++q) {
    unsigned short* Or = out + (size_t)(row0 + q) * HIDDEN + colbase;
    Or[l]      = f2bf(v0[q]);
    Or[64 + l] = f2bf(v1[q]);
  }
}

// ---------------- inter' = R_d( silu(gate)*up*wgt / ch_d ) -> bf16 ----------------
__global__ __launch_bounds__(256) void k_silu2(
    const float* __restrict__ h, const float* __restrict__ pw,
    const float* __restrict__ rch, const float4* __restrict__ tbl,
    unsigned short* __restrict__ out) {
  __shared__ float4 tl[NROT * 128];
  const int wv = threadIdx.x >> 6, l = threadIdx.x & 63;
  const int g = blockIdx.x % 6;                  // INTERM/128 groups
  const int rowblk = blockIdx.x / 6;
  const int row0 = rowblk * 16 + wv * 4;
  const int colbase = g << 7;
  tl[threadIdx.x]       = tbl[(size_t)g * NROT * 128 + threadIdx.x];
  tl[256 + threadIdx.x] = tbl[(size_t)g * NROT * 128 + 256 + threadIdx.x];
  __syncthreads();
  const float i0 = rch[colbase + l], i1 = rch[colbase + 64 + l];
  float v0[4], v1[4];
#pragma unroll
  for (int q = 0; q < 4; ++q) {
    const int row = row0 + q;
    const float wgt = pw[row];
    const float* hr = h + (size_t)row * 1536 + colbase;
    const float g0 = hr[l], g1 = hr[64 + l];
    const float u0 = hr[768 + l], u1 = hr[768 + 64 + l];
    v0[q] = g0 / (1.0f + expf(-g0)) * u0 * wgt * i0;
    v1[q] = g1 / (1.0f + expf(-g1)) * u1 * wgt * i1;
  }
  FWD_ROT(tl, v0, v1)
#pragma unroll
  for (int q = 0; q < 4; ++q) {
    unsigned short* Or = out + (size_t)(row0 + q) * INTERM + colbase;
    Or[l]      = f2bf(v0[q]);
    Or[64 + l] = f2bf(v1[q]);
  }
}

// ---------------- expert-segmented GEMM: C = A * B^T ----------------
// 256x256 tile, BK=64, 8 waves (2x4), 8-phase schedule (4 phases/K-tile x 2 dbuf),
// counted vmcnt(4) per K-tile boundary, raw s_barrier pairs, setprio around MFMA.
// LDS 128KB: [buf][A/B][ksub][256 rows][32 cols bf16], linear for global_load_lds;
// bank swizzle (T2, rule-21): source chunk pre-XOR (c ^= row&3), ds_read same XOR.
// Stage pipeline per tile t: p1:A-kh1(t+1)->alt  p2:B-kh1(t+1)->alt
//                            p3:A-kh0(t+2)->cur  p4:B-kh0(t+2)->cur
// (kh0 regions of cur are free after p2: ksub0 reads retired at p2's lgkmcnt+barrier)
// MODE 0: gather A rows by token (pt>>1), store segment-ordered C.
// MODE 1: A rows segment-ordered, store pair-indexed C (NO atomics).
template <int MODE>
__launch_bounds__(512, 2)
__global__ void k_gemm(const unsigned short* __restrict__ A,
                       const unsigned short* __restrict__ Bw,
                       float* __restrict__ C,
                       const int* __restrict__ pt,
                       const int* __restrict__ off,
                       const int* __restrict__ cnt,
                       const int* __restrict__ tmap,
                       const int* __restrict__ nv) {
  constexpr int K = MODE ? INTERM : HIDDEN;
  constexpr int N = MODE ? HIDDEN : 2 * INTERM;
  constexpr int XW = MODE ? 8 : 6;            // n-tiles of 256
  constexpr int NT = K / 64;                  // K-tiles (32 / 12, both even, >=3)

  const int hw  = blockIdx.x + XW * blockIdx.y;
  const int xcd = hw & 7;
  const int pos = hw >> 3;
  const int nvalid = nv[0];
  const int q8 = nvalid >> 3, r8 = nvalid & 7;
  const int rs = q8 + (xcd < r8 ? 1 : 0);
  const int y0 = xcd * q8 + (xcd < r8 ? xcd : r8);
  if (pos >= rs * XW) return;
  const int xg = pos % XW;
  const int yg = y0 + pos / XW;
  const int tm = tmap[yg];
  if (tm < 0) return;
  const int e = tm >> 16;
  const int m0 = (tm & 0xffff) << 8;
  const int count = cnt[e];
  const int seg = off[e];
  const int n0 = xg * 256;
  const unsigned short* Be = Bw + (size_t)e * N * K;

  __shared__ unsigned short lds[65536];       // 128 KiB

  const int tid = threadIdx.x;
  const int w = tid >> 6, l = tid & 63;
  const int wm = w >> 2, wn = w & 3;
  const int w512 = w * 512;

  // ---- stage source pointers (pre-swizzled chunk: c ^ (row&3)) ----
  const int sr = tid >> 2;                              // stage row 0..127
  const int cs = (((tid & 3) ^ (sr & 3))) * 8;          // element offset of 16B chunk
  int pA0 = m0 + sr;        if (pA0 > count - 1) pA0 = count - 1;
  int pA1 = m0 + sr + 128;  if (pA1 > count - 1) pA1 = count - 1;
  size_t arow0, arow1;
  if (MODE == 0) { arow0 = (size_t)(pt[seg + pA0] >> 1); arow1 = (size_t)(pt[seg + pA1] >> 1); }
  else           { arow0 = (size_t)(seg + pA0); arow1 = (size_t)(seg + pA1); }
  const unsigned short* paS0 = A + arow0 * K + cs;
  const unsigned short* paS1 = A + arow1 * K + cs;
  const unsigned short* pbS0 = Be + (size_t)(n0 + sr) * K + cs;
  const unsigned short* pbS1 = Be + (size_t)(n0 + sr + 128) * K + cs;

  // ---- fragment read offsets (same XOR) ----
  const int cswz  = ((l >> 4) ^ (l & 3)) * 8;
  const int abase = (wm * 128 + (l & 15)) * 32 + cswz;            // within A ksub half
  const int bbase = (wn * 64  + (l & 15)) * 32 + cswz + 16384;    // +B offset folded

  f32x4 acc[8][4];
#pragma unroll
  for (int i = 0; i < 8; ++i)
#pragma unroll
    for (int j = 0; j < 4; ++j) acc[i][j] = (f32x4)0.0f;

  // layout (ushort units): buf*32768 + {A:0,B:16384} + ksub*8192 + row*32 + chunk*8
#define STG_A(dst, koff) do { \
    async16(paS0 + (koff), &lds[(dst) + w512]); \
    async16(paS1 + (koff), &lds[(dst) + 4096 + w512]); } while (0)
#define STG_B(dst, koff) do { \
    async16(pbS0 + (koff), &lds[(dst) + w512]); \
    async16(pbS1 + (koff), &lds[(dst) + 4096 + w512]); } while (0)

  // prologue: t0 fully + t1 kh0   (12 vmem instr; newest 4 = t1 kh0 stay in flight)
  STG_A(0,     0);  STG_B(16384,       0);
  STG_A(8192,  32); STG_B(16384+8192,  32);
  STG_A(32768, 64); STG_B(32768+16384, 64);
  asm volatile("s_waitcnt vmcnt(4)" ::: "memory");
  __builtin_amdgcn_s_barrier();

  for (int t = 0; t < NT; ++t) {
    const int base = (t & 1) << 15;            // 0 / 32768
    const int alt  = base ^ 32768;
    const int k1 = (t + 1) * 64, k2 = (t + 2) * 64;
    bf16x8 a[4], bq[4];

    // ---------------- phase 1: ksub0, m-half0 (+B ksub0) ----------------
#pragma unroll
    for (int ii = 0; ii < 4; ++ii) a[ii]  = *(const bf16x8*)&lds[base + abase + ii * 512];
#pragma unroll
    for (int j = 0; j < 4; ++j)    bq[j]  = *(const bf16x8*)&lds[base + bbase + j * 512];
    if (t + 1 < NT) STG_A(alt + 8192, k1 + 32);            // A-kh1(t+1) -> idle buf
    __builtin_amdgcn_s_barrier();
    asm volatile("s_waitcnt lgkmcnt(0)" ::: "memory");
    __builtin_amdgcn_sched_barrier(0);
    __builtin_amdgcn_s_setprio(1);
#pragma unroll
    for (int ii = 0; ii < 4; ++ii)
#pragma unroll
      for (int j = 0; j < 4; ++j)
        acc[ii][j] = __builtin_amdgcn_mfma_f32_16x16x32_bf16(a[ii], bq[j], acc[ii][j], 0, 0, 0);
    __builtin_amdgcn_s_setprio(0);
    __builtin_amdgcn_s_barrier();

    // ---------------- phase 2: ksub0, m-half1 ----------------
#pragma unroll
    for (int ii = 0; ii < 4; ++ii) a[ii] = *(const bf16x8*)&lds[base + abase + (4 + ii) * 512];
    if (t + 1 < NT) STG_B(alt + 16384 + 8192, k1 + 32);    // B-kh1(t+1) -> idle buf
    __builtin_amdgcn_s_barrier();
    asm volatile("s_waitcnt lgkmcnt(0)" ::: "memory");
    __builtin_amdgcn_sched_barrier(0);
    __builtin_amdgcn_s_setprio(1);
#pragma unroll
    for (int ii = 0; ii < 4; ++ii)
#pragma unroll
      for (int j = 0; j < 4; ++j)
        acc[4 + ii][j] = __builtin_amdgcn_mfma_f32_16x16x32_bf16(a[ii], bq[j], acc[4 + ii][j], 0, 0, 0);
    __builtin_amdgcn_s_setprio(0);
    __builtin_amdgcn_s_barrier();

    // ---------------- phase 3: ksub1, m-half0 (+B ksub1) ----------------
#pragma unroll
    for (int ii = 0; ii < 4; ++ii) a[ii] = *(const bf16x8*)&lds[base + 8192 + abase + ii * 512];
#pragma unroll
    for (int j = 0; j < 4; ++j)    bq[j] = *(const bf16x8*)&lds[base + 8192 + bbase + j * 512];
    if (t + 2 < NT) STG_A(base, k2);                       // A-kh0(t+2) -> cur buf (kh0 free)
    __builtin_amdgcn_s_barrier();
    asm volatile("s_waitcnt lgkmcnt(0)" ::: "memory");
    __builtin_amdgcn_sched_barrier(0);
    __builtin_amdgcn_s_setprio(1);
#pragma unroll
    for (int ii = 0; ii < 4; ++ii)
#pragma unroll
      for (int j = 0; j < 4; ++j)
        acc[ii][j] = __builtin_amdgcn_mfma_f32_16x16x32_bf16(a[ii], bq[j], acc[ii][j], 0, 0, 0);
    __builtin_amdgcn_s_setprio(0);
    __builtin_amdgcn_s_barrier();

    // ---------------- phase 4: ksub1, m-half1 ----------------
#pragma unroll
    for (int ii = 0; ii < 4; ++ii) a[ii] = *(const bf16x8*)&lds[base + 8192 + abase + (4 + ii) * 512];
    if (t + 2 < NT) STG_B(base + 16384, k2);               // B-kh0(t+2) -> cur buf
    __builtin_amdgcn_s_barrier();
    asm volatile("s_waitcnt lgkmcnt(0)" ::: "memory");
    __builtin_amdgcn_sched_barrier(0);
    __builtin_amdgcn_s_setprio(1);
#pragma unroll
    for (int ii = 0; ii < 4; ++ii)
#pragma unroll
      for (int j = 0; j < 4; ++j)
        acc[4 + ii][j] = __builtin_amdgcn_mfma_f32_16x16x32_bf16(a[ii], bq[j], acc[4 + ii][j], 0, 0, 0);
    __builtin_amdgcn_s_setprio(0);
    if (t + 1 < NT) {                       // tile boundary: counted vmcnt (T4)
      if (t + 1 == NT - 1) asm volatile("s_waitcnt vmcnt(0)" ::: "memory");
      else                 asm volatile("s_waitcnt vmcnt(4)" ::: "memory");
    }
    __builtin_amdgcn_s_barrier();
  }
#undef STG_A
#undef STG_B

  // ---------------- epilogue ----------------
  const int mb = wm * 128 + (l >> 4) * 4;
  const int nb = n0 + wn * 64 + (l & 15);
#pragma unroll
  for (int i = 0; i < 8; ++i) {
#pragma unroll
    for (int j = 0; j < 4; ++j) {
#pragma unroll
      for (int r = 0; r < 4; ++r) {
        const int mm = m0 + mb + i * 16 + r;
        if (mm < count) {
          const int nn = nb + j * 16;
          if (MODE == 0) {
            C[(size_t)(seg + mm) * N + nn] = acc[i][j][r];
          } else {
            C[(size_t)pt[seg + mm] * N + nn] = acc[i][j][r];
          }
        }
      }
    }
  }
}

// ---------------- out[t] = ybuf[2t] + ybuf[2t+1] ----------------
__global__ __launch_bounds__(256) void k_combine(const float4* __restrict__ y,
                                                 float4* __restrict__ out) {
  const int t = blockIdx.x;                       // token
  const float4* y0 = y + (size_t)(2 * t) * (HIDDEN / 4);
  const float4* y1 = y + (size_t)(2 * t + 1) * (HIDDEN / 4);
  float4* o = out + (size_t)t * (HIDDEN / 4);
#pragma unroll
  for (int q = 0; q < 2; ++q) {
    const int c = threadIdx.x + q * 256;          // 512 float4 per token
    const float4 a = y0[c], b = y1[c];
    o[c] = make_float4(a.x + b.x, a.y + b.y, a.z + b.z, a.w + b.w);
  }
}

// ---------------- launch ----------------
extern "C" void kernel_launch(void* const* d_in, const int* in_sizes, int n_in,
                              void* d_out, int out_size, void* d_ws, size_t ws_size,
                              hipStream_t stream) {
  const float* hs  = (const float*)d_in[0];
  const int*   tki = (const int*)d_in[1];
  const float* tkw = (const float*)d_in[2];
  const float* guw = (const float*)d_in[3];
  const float* dww = (const float*)d_in[4];
  const int*   gupr= (const int*)d_in[5];
  const float* gua = (const float*)d_in[6];
  const int*   dwp = (const int*)d_in[7];
  const float* dwa = (const float*)d_in[8];
  const float* gus = (const float*)d_in[9];
  const float* dwsc= (const float*)d_in[10];
  float* out = (float*)d_out;
  char* ws = (char*)d_ws;

  unsigned short* gup_bf = (unsigned short*)(ws + 0);          //  50,331,648 B
  unsigned short* dwn_bf = (unsigned short*)(ws + 50331648);   //  25,165,824 B
  unsigned short* x_bf   = (unsigned short*)(ws + 75497472);   //  16,777,216 B
  float*          hbuf   = (float*)(ws + 92274688);            //  50,331,648 B
  unsigned short* interb = (unsigned short*)(ws + 142606336);  //  12,582,912 B
  // ybuf (8192 x 2048 f32 = 67,108,864 B) reuses x_bf + hbuf (both dead after k_silu2)
  float*          ybuf   = (float*)(ws + 75497472);
  int*            pt     = (int*)(ws + 155189248);             //  32,768 B
  float*          pw     = (float*)(ws + 155222016);           //  32,768 B
  int*            cnt    = (int*)(ws + 155254784);             //  cnt/off/cur/tmap/nv (<4 KiB)
  int*            off    = cnt + 8;
  int*            cur    = cnt + 16;
  int*            tmap   = cnt + 24;
  int*            nv     = cnt + 120;
  float4*         tg     = (float4*)(ws + 155258880);          // 131,072 B (16 grp)
  float4*         td     = (float4*)(ws + 155389952);          //  49,152 B (6 grp)
  float*          grch   = (float*)(ws + 155439104);           //   8,192 B
  float*          drch   = (float*)(ws + 155447296);           //   3,072 B

  (void)hipMemsetAsync(cnt, 0, 32, stream);

  k_hist<<<32, 256, 0, stream>>>(tki, cnt);
  k_scan<<<1, 64, 0, stream>>>(cnt, off, cur, tmap, nv);
  k_scatter<<<32, 256, 0, stream>>>(tki, tkw, off, cur, pt, pw);
  k_tbl<<<16, 256, 0, stream>>>(gupr, gua, dwp, dwa, gus, dwsc, tg, td, grch, drch);
  k_rotx<<<4096, 256, 0, stream>>>(hs, grch, tg, x_bf);
  k_quant<<<12288, 256, 0, stream>>>(guw, tg, gus, gup_bf, HIDDEN, 16);
  k_quant<<<6144, 256, 0, stream>>>(dww, td, dwsc, dwn_bf, INTERM, 6);
  k_gemm<0><<<dim3(6, MAXT), 512, 0, stream>>>(x_bf, gup_bf, hbuf, pt, off, cnt, tmap, nv);
  k_silu2<<<3072, 256, 0, stream>>>(hbuf, pw, drch, td, interb);
  k_gemm<1><<<dim3(8, MAXT), 512, 0, stream>>>(interb, dwn_bf, ybuf, pt, off, cnt, tmap, nv);
  k_combine<<<T_TOKENS, 256, 0, stream>>>((const float4*)ybuf, (float4*)out);
}

// Round 5
// 538.305 us; speedup vs baseline: 1.0378x; 1.0188x over previous
//
#include <hip/hip_runtime.h>

#define T_TOKENS 4096
#define HIDDEN   2048
#define INTERM   768
#define NE       8
#define NPAIR    8192   // T_TOKENS * TOP_K
#define NROT     4
#define MAXT     40     // max total 256-row m-tiles across experts (32 + 8)

typedef __bf16 bf16x8 __attribute__((ext_vector_type(8)));
typedef float  f32x4  __attribute__((ext_vector_type(4)));

__device__ __forceinline__ unsigned short f2bf(float f) {
  unsigned u = __float_as_uint(f);
  u += 0x7fffu + ((u >> 16) & 1u);   // round-to-nearest-even (finite inputs only)
  return (unsigned short)(u >> 16);
}

__device__ __forceinline__ void async16(const void* g, void* l) {
  __builtin_amdgcn_global_load_lds((const __attribute__((address_space(1))) void*)g,
                                   (__attribute__((address_space(3))) void*)l, 16, 0, 0);
}

// ---------------- routing: histogram / scan+tilemap / scatter ----------------
__global__ void k_hist(const int* __restrict__ idx, int* __restrict__ cnt) {
  const int t = blockIdx.x * 256 + threadIdx.x;
  if (t < NPAIR) atomicAdd(&cnt[idx[t]], 1);
}

__global__ void k_scan(const int* __restrict__ cnt, int* __restrict__ off,
                       int* __restrict__ cur, int* __restrict__ tmap,
                       int* __restrict__ nv) {
  if (threadIdx.x == 0) {
    int a = 0, tt = 0;
    for (int e = 0; e < NE; ++e) {
      off[e] = a; cur[e] = 0;
      const int c = cnt[e];
      for (int m = 0; m < c; m += 256) tmap[tt++] = (e << 16) | (m >> 8);
      a += c;
    }
    nv[0] = tt;                      // number of VALID 256-row m-tiles
    for (; tt < MAXT; ++tt) tmap[tt] = -1;
  }
}

// pt[pos] = ORIGINAL pair index t (token = t>>1, slot = t&1)
__global__ void k_scatter(const int* __restrict__ idx, const float* __restrict__ wts,
                          const int* __restrict__ off, int* __restrict__ cur,
                          int* __restrict__ pt, float* __restrict__ pw) {
  const int t = blockIdx.x * 256 + threadIdx.x;
  if (t < NPAIR) {
    const int e = idx[t];
    const int pos = off[e] + atomicAdd(&cur[e], 1);
    pt[pos] = t;          // pair id (carries token and slot)
    pw[pos] = wts[t];     // routing weight
  }
}

// ---------------- build per-destination rotation tables + recip channel scales ----
// entry (group g, rot r, dest d): {cos, signed_sin, partner, 0};
// forward: new[d] = cos*old[d] + signed_sin*old[partner]
__global__ void k_tbl(const int* __restrict__ gp, const float* __restrict__ ga,
                      const int* __restrict__ dp, const float* __restrict__ da,
                      const float* __restrict__ gch, const float* __restrict__ dch,
                      float4* __restrict__ tg, float4* __restrict__ td,
                      float* __restrict__ grch, float* __restrict__ drch) {
  const int t = blockIdx.x * 256 + threadIdx.x;
  if (t < NROT * (HIDDEN / 2)) {
    const int r = t >> 10, s = t & 1023;          // slot s over 1024 pairs
    const int grp = s >> 6;
    const int i = gp[r * HIDDEN + 2 * s], j = gp[r * HIDDEN + 2 * s + 1];
    const float a = ga[r * (HIDDEN / 2) + s];
    const float c = cosf(a), sn = sinf(a);
    tg[(grp * NROT + r) * 128 + i] = make_float4(c, -sn, __int_as_float(j), 0.f);
    tg[(grp * NROT + r) * 128 + j] = make_float4(c,  sn, __int_as_float(i), 0.f);
  }
  if (t < NROT * (INTERM / 2)) {
    const int r = t / (INTERM / 2), s = t - r * (INTERM / 2);
    const int grp = s >> 6;
    const int i = dp[r * INTERM + 2 * s], j = dp[r * INTERM + 2 * s + 1];
    const float a = da[r * (INTERM / 2) + s];
    const float c = cosf(a), sn = sinf(a);
    td[(grp * NROT + r) * 128 + i] = make_float4(c, -sn, __int_as_float(j), 0.f);
    td[(grp * NROT + r) * 128 + j] = make_float4(c,  sn, __int_as_float(i), 0.f);
  }
  if (t < HIDDEN) grch[t] = 1.0f / gch[t];
  if (t < INTERM) drch[t] = 1.0f / dch[t];
}

// helper: 4 forward rotation passes on (v0,v1) held across the wave (128-group)
#define FWD_ROT(tl, v0, v1)                                                     \
  _Pragma("unroll")                                                             \
  for (int r = 0; r < NROT; ++r) {                                              \
    const float4 e0 = tl[r * 128 + l];                                          \
    const float4 e1 = tl[r * 128 + 64 + l];                                     \
    const int p0 = __float_as_int(e0.z), p1 = __float_as_int(e1.z);             \
    const int a0 = (p0 & 63) << 2, a1 = (p1 & 63) << 2;                         \
    _Pragma("unroll")                                                           \
    for (int q = 0; q < 4; ++q) {                                               \
      const int x0 = __float_as_int(v0[q]), x1 = __float_as_int(v1[q]);         \
      const float lo0 = __int_as_float(__builtin_amdgcn_ds_bpermute(a0, x0));   \
      const float hi0 = __int_as_float(__builtin_amdgcn_ds_bpermute(a0, x1));   \
      const float lo1 = __int_as_float(__builtin_amdgcn_ds_bpermute(a1, x0));   \
      const float hi1 = __int_as_float(__builtin_amdgcn_ds_bpermute(a1, x1));   \
      const float op0 = (p0 & 64) ? hi0 : lo0;                                  \
      const float op1 = (p1 & 64) ? hi1 : lo1;                                  \
      {                                                                         \
        _Pragma("clang fp contract(off)")                                       \
        v0[q] = e0.x * v0[q] + e0.y * op0;                                      \
        v1[q] = e1.x * v1[q] + e1.y * op1;                                      \
      }                                                                         \
    }                                                                           \
  }

// ---------------- weight pseudo-quantize (forward only, outputs rotated q) ------
__global__ __launch_bounds__(256) void k_quant(
    const float* __restrict__ W, const float4* __restrict__ tbl,
    const float* __restrict__ ch, unsigned short* __restrict__ out, int In, int G) {
  __shared__ float4 tl[NROT * 128];
  const int wv = threadIdx.x >> 6, l = threadIdx.x & 63;
  const int g = blockIdx.x % G;
  const int rowblk = blockIdx.x / G;
  const int row0 = rowblk * 16 + wv * 4;
  const int colbase = g << 7;
  tl[threadIdx.x]       = tbl[(size_t)g * NROT * 128 + threadIdx.x];
  tl[256 + threadIdx.x] = tbl[(size_t)g * NROT * 128 + 256 + threadIdx.x];
  __syncthreads();
  const float c0 = ch[colbase + l], c1 = ch[colbase + 64 + l];
  float v0[4], v1[4];
#pragma unroll
  for (int q = 0; q < 4; ++q) {
#pragma clang fp contract(off)
    const float* Wr = W + (size_t)(row0 + q) * In + colbase;
    v0[q] = Wr[l] * c0;
    v1[q] = Wr[64 + l] * c1;
  }
  FWD_ROT(tl, v0, v1)
  // fake quant per row; output stays in rotated space
#pragma unroll
  for (int q = 0; q < 4; ++q) {
    float mn = fminf(v0[q], v1[q]), mx = fmaxf(v0[q], v1[q]);
#pragma unroll
    for (int o = 32; o > 0; o >>= 1) {
      mn = fminf(mn, __shfl_xor(mn, o));
      mx = fmaxf(mx, __shfl_xor(mx, o));
    }
    {
#pragma clang fp contract(off)
      const float scale = fmaxf(mx - mn, 1e-5f) / 15.0f;
      const float zero = rintf(-mn / scale);
      const float q0 = fminf(fmaxf(rintf(v0[q] / scale) + zero, 0.0f), 15.0f);
      const float q1 = fminf(fmaxf(rintf(v1[q] / scale) + zero, 0.0f), 15.0f);
      v0[q] = (q0 - zero) * scale;
      v1[q] = (q1 - zero) * scale;
    }
  }
#pragma unroll
  for (int q = 0; q < 4; ++q) {
    unsigned short* Or = out + (size_t)(row0 + q) * In + colbase;
    Or[l]      = f2bf(v0[q]);
    Or[64 + l] = f2bf(v1[q]);
  }
}

// ---------------- x' = R(x / ch) -> bf16 ----------------
__global__ __launch_bounds__(256) void k_rotx(
    const float* __restrict__ X, const float* __restrict__ rch,
    const float4* __restrict__ tbl, unsigned short* __restrict__ out) {
  __shared__ float4 tl[NROT * 128];
  const int wv = threadIdx.x >> 6, l = threadIdx.x & 63;
  const int g = blockIdx.x % 16;                 // HIDDEN/128 groups
  const int rowblk = blockIdx.x / 16;
  const int row0 = rowblk * 16 + wv * 4;
  const int colbase = g << 7;
  tl[threadIdx.x]       = tbl[(size_t)g * NROT * 128 + threadIdx.x];
  tl[256 + threadIdx.x] = tbl[(size_t)g * NROT * 128 + 256 + threadIdx.x];
  __syncthreads();
  const float i0 = rch[colbase + l], i1 = rch[colbase + 64 + l];
  float v0[4], v1[4];
#pragma unroll
  for (int q = 0; q < 4; ++q) {
    const float* Xr = X + (size_t)(row0 + q) * HIDDEN + colbase;
    v0[q] = Xr[l] * i0;
    v1[q] = Xr[64 + l] * i1;
  }
  FWD_ROT(tl, v0, v1)
#pragma unroll
  for (int q = 0; q < 4; ++q) {
    unsigned short* Or = out + (size_t)(row0 + q) * HIDDEN + colbase;
    Or[l]      = f2bf(v0[q]);
    Or[64 + l] = f2bf(v1[q]);
  }
}

// ---------------- inter' = R_d( silu(gate)*up*wgt / ch_d ) -> bf16 ----------------
__global__ __launch_bounds__(256) void k_silu2(
    const float* __restrict__ h, const float* __restrict__ pw,
    const float* __restrict__ rch, const float4* __restrict__ tbl,
    unsigned short* __restrict__ out) {
  __shared__ float4 tl[NROT * 128];
  const int wv = threadIdx.x >> 6, l = threadIdx.x & 63;
  const int g = blockIdx.x % 6;                  // INTERM/128 groups
  const int rowblk = blockIdx.x / 6;
  const int row0 = rowblk * 16 + wv * 4;
  const int colbase = g << 7;
  tl[threadIdx.x]       = tbl[(size_t)g * NROT * 128 + threadIdx.x];
  tl[256 + threadIdx.x] = tbl[(size_t)g * NROT * 128 + 256 + threadIdx.x];
  __syncthreads();
  const float i0 = rch[colbase + l], i1 = rch[colbase + 64 + l];
  float v0[4], v1[4];
#pragma unroll
  for (int q = 0; q < 4; ++q) {
    const int row = row0 + q;
    const float wgt = pw[row];
    const float* hr = h + (size_t)row * 1536 + colbase;
    const float g0 = hr[l], g1 = hr[64 + l];
    const float u0 = hr[768 + l], u1 = hr[768 + 64 + l];
    v0[q] = g0 / (1.0f + expf(-g0)) * u0 * wgt * i0;
    v1[q] = g1 / (1.0f + expf(-g1)) * u1 * wgt * i1;
  }
  FWD_ROT(tl, v0, v1)
#pragma unroll
  for (int q = 0; q < 4; ++q) {
    unsigned short* Or = out + (size_t)(row0 + q) * INTERM + colbase;
    Or[l]      = f2bf(v0[q]);
    Or[64 + l] = f2bf(v1[q]);
  }
}

// ---------------- expert-segmented GEMM: C = A * B^T ----------------
// 256x256 tile, BK=64, 8 waves (2x4), 8-phase schedule (4 phases/K-tile x 2 dbuf),
// counted vmcnt(4) per K-tile boundary, raw s_barrier pairs, setprio around MFMA.
// LDS 128KB: [buf][A/B][ksub][256 rows][32 cols bf16], linear for global_load_lds.
// Bank swizzle (T2, rule-21 both-sides): chunk ^= (row>>1)&3.
//   Read pattern: lane l -> row l&15 (64B rows), chunk q=l>>4. Bank-quad =
//   (4r + q^((r>>1)&3)) % 8 is a permutation within every 8-lane group ->
//   conflict-FREE ds_read_b128 (prev round's ^(row&3) left 4-way conflicts).
// Stage pipeline per tile t: p1:A-kh1(t+1)->alt  p2:B-kh1(t+1)->alt
//                            p3:A-kh0(t+2)->cur  p4:B-kh0(t+2)->cur
// MODE 0: gather A rows by token (pt>>1), store segment-ordered C.
// MODE 1: A rows segment-ordered, store pair-indexed C (NO atomics).
template <int MODE>
__launch_bounds__(512, 2)
__global__ void k_gemm(const unsigned short* __restrict__ A,
                       const unsigned short* __restrict__ Bw,
                       float* __restrict__ C,
                       const int* __restrict__ pt,
                       const int* __restrict__ off,
                       const int* __restrict__ cnt,
                       const int* __restrict__ tmap,
                       const int* __restrict__ nv) {
  constexpr int K = MODE ? INTERM : HIDDEN;
  constexpr int N = MODE ? HIDDEN : 2 * INTERM;
  constexpr int XW = MODE ? 8 : 6;            // n-tiles of 256
  constexpr int NT = K / 64;                  // K-tiles (32 / 12, both even, >=3)

  const int hw  = blockIdx.x + XW * blockIdx.y;
  const int xcd = hw & 7;
  const int pos = hw >> 3;
  const int nvalid = nv[0];
  const int q8 = nvalid >> 3, r8 = nvalid & 7;
  const int rs = q8 + (xcd < r8 ? 1 : 0);
  const int y0 = xcd * q8 + (xcd < r8 ? xcd : r8);
  if (pos >= rs * XW) return;
  const int xg = pos % XW;
  const int yg = y0 + pos / XW;
  const int tm = tmap[yg];
  if (tm < 0) return;
  const int e = tm >> 16;
  const int m0 = (tm & 0xffff) << 8;
  const int count = cnt[e];
  const int seg = off[e];
  const int n0 = xg * 256;
  const unsigned short* Be = Bw + (size_t)e * N * K;

  __shared__ unsigned short lds[65536];       // 128 KiB

  const int tid = threadIdx.x;
  const int w = tid >> 6, l = tid & 63;
  const int wm = w >> 2, wn = w & 3;
  const int w512 = w * 512;

  // ---- stage source pointers (pre-swizzled chunk: c ^ ((row>>1)&3)) ----
  const int sr = tid >> 2;                              // stage row 0..127
  const int cs = (((tid & 3) ^ ((tid >> 3) & 3))) * 8;  // element offset of 16B chunk
  int pA0 = m0 + sr;        if (pA0 > count - 1) pA0 = count - 1;
  int pA1 = m0 + sr + 128;  if (pA1 > count - 1) pA1 = count - 1;
  size_t arow0, arow1;
  if (MODE == 0) { arow0 = (size_t)(pt[seg + pA0] >> 1); arow1 = (size_t)(pt[seg + pA1] >> 1); }
  else           { arow0 = (size_t)(seg + pA0); arow1 = (size_t)(seg + pA1); }
  const unsigned short* paS0 = A + arow0 * K + cs;
  const unsigned short* paS1 = A + arow1 * K + cs;
  const unsigned short* pbS0 = Be + (size_t)(n0 + sr) * K + cs;
  const unsigned short* pbS1 = Be + (size_t)(n0 + sr + 128) * K + cs;

  // ---- fragment read offsets (same XOR: q ^ ((row>>1)&3), row%16 = l&15) ----
  const int cswz  = ((l >> 4) ^ (((l & 15) >> 1) & 3)) * 8;
  const int abase = (wm * 128 + (l & 15)) * 32 + cswz;            // within A ksub half
  const int bbase = (wn * 64  + (l & 15)) * 32 + cswz + 16384;    // +B offset folded

  f32x4 acc[8][4];
#pragma unroll
  for (int i = 0; i < 8; ++i)
#pragma unroll
    for (int j = 0; j < 4; ++j) acc[i][j] = (f32x4)0.0f;

  // layout (ushort units): buf*32768 + {A:0,B:16384} + ksub*8192 + row*32 + chunk*8
#define STG_A(dst, koff) do { \
    async16(paS0 + (koff), &lds[(dst) + w512]); \
    async16(paS1 + (koff), &lds[(dst) + 4096 + w512]); } while (0)
#define STG_B(dst, koff) do { \
    async16(pbS0 + (koff), &lds[(dst) + w512]); \
    async16(pbS1 + (koff), &lds[(dst) + 4096 + w512]); } while (0)

  // prologue: t0 fully + t1 kh0   (12 vmem instr; newest 4 = t1 kh0 stay in flight)
  STG_A(0,     0);  STG_B(16384,       0);
  STG_A(8192,  32); STG_B(16384+8192,  32);
  STG_A(32768, 64); STG_B(32768+16384, 64);
  asm volatile("s_waitcnt vmcnt(4)" ::: "memory");
  __builtin_amdgcn_s_barrier();

  for (int t = 0; t < NT; ++t) {
    const int base = (t & 1) << 15;            // 0 / 32768
    const int alt  = base ^ 32768;
    const int k1 = (t + 1) * 64, k2 = (t + 2) * 64;
    bf16x8 a[4], bq[4];

    // ---------------- phase 1: ksub0, m-half0 (+B ksub0) ----------------
#pragma unroll
    for (int ii = 0; ii < 4; ++ii) a[ii]  = *(const bf16x8*)&lds[base + abase + ii * 512];
#pragma unroll
    for (int j = 0; j < 4; ++j)    bq[j]  = *(const bf16x8*)&lds[base + bbase + j * 512];
    if (t + 1 < NT) STG_A(alt + 8192, k1 + 32);            // A-kh1(t+1) -> idle buf
    __builtin_amdgcn_s_barrier();
    asm volatile("s_waitcnt lgkmcnt(0)" ::: "memory");
    __builtin_amdgcn_sched_barrier(0);
    __builtin_amdgcn_s_setprio(1);
#pragma unroll
    for (int ii = 0; ii < 4; ++ii)
#pragma unroll
      for (int j = 0; j < 4; ++j)
        acc[ii][j] = __builtin_amdgcn_mfma_f32_16x16x32_bf16(a[ii], bq[j], acc[ii][j], 0, 0, 0);
    __builtin_amdgcn_s_setprio(0);
    __builtin_amdgcn_s_barrier();

    // ---------------- phase 2: ksub0, m-half1 ----------------
#pragma unroll
    for (int ii = 0; ii < 4; ++ii) a[ii] = *(const bf16x8*)&lds[base + abase + (4 + ii) * 512];
    if (t + 1 < NT) STG_B(alt + 16384 + 8192, k1 + 32);    // B-kh1(t+1) -> idle buf
    __builtin_amdgcn_s_barrier();
    asm volatile("s_waitcnt lgkmcnt(0)" ::: "memory");
    __builtin_amdgcn_sched_barrier(0);
    __builtin_amdgcn_s_setprio(1);
#pragma unroll
    for (int ii = 0; ii < 4; ++ii)
#pragma unroll
      for (int j = 0; j < 4; ++j)
        acc[4 + ii][j] = __builtin_amdgcn_mfma_f32_16x16x32_bf16(a[ii], bq[j], acc[4 + ii][j], 0, 0, 0);
    __builtin_amdgcn_s_setprio(0);
    __builtin_amdgcn_s_barrier();

    // ---------------- phase 3: ksub1, m-half0 (+B ksub1) ----------------
#pragma unroll
    for (int ii = 0; ii < 4; ++ii) a[ii] = *(const bf16x8*)&lds[base + 8192 + abase + ii * 512];
#pragma unroll
    for (int j = 0; j < 4; ++j)    bq[j] = *(const bf16x8*)&lds[base + 8192 + bbase + j * 512];
    if (t + 2 < NT) STG_A(base, k2);                       // A-kh0(t+2) -> cur buf (kh0 free)
    __builtin_amdgcn_s_barrier();
    asm volatile("s_waitcnt lgkmcnt(0)" ::: "memory");
    __builtin_amdgcn_sched_barrier(0);
    __builtin_amdgcn_s_setprio(1);
#pragma unroll
    for (int ii = 0; ii < 4; ++ii)
#pragma unroll
      for (int j = 0; j < 4; ++j)
        acc[ii][j] = __builtin_amdgcn_mfma_f32_16x16x32_bf16(a[ii], bq[j], acc[ii][j], 0, 0, 0);
    __builtin_amdgcn_s_setprio(0);
    __builtin_amdgcn_s_barrier();

    // ---------------- phase 4: ksub1, m-half1 ----------------
#pragma unroll
    for (int ii = 0; ii < 4; ++ii) a[ii] = *(const bf16x8*)&lds[base + 8192 + abase + (4 + ii) * 512];
    if (t + 2 < NT) STG_B(base + 16384, k2);               // B-kh0(t+2) -> cur buf
    __builtin_amdgcn_s_barrier();
    asm volatile("s_waitcnt lgkmcnt(0)" ::: "memory");
    __builtin_amdgcn_sched_barrier(0);
    __builtin_amdgcn_s_setprio(1);
#pragma unroll
    for (int ii = 0; ii < 4; ++ii)
#pragma unroll
      for (int j = 0; j < 4; ++j)
        acc[4 + ii][j] = __builtin_amdgcn_mfma_f32_16x16x32_bf16(a[ii], bq[j], acc[4 + ii][j], 0, 0, 0);
    __builtin_amdgcn_s_setprio(0);
    if (t + 1 < NT) {                       // tile boundary: counted vmcnt (T4)
      if (t + 1 == NT - 1) asm volatile("s_waitcnt vmcnt(0)" ::: "memory");
      else                 asm volatile("s_waitcnt vmcnt(4)" ::: "memory");
    }
    __builtin_amdgcn_s_barrier();
  }
#undef STG_A
#undef STG_B

  // ---------------- epilogue ----------------
  const int mb = wm * 128 + (l >> 4) * 4;
  const int nb = n0 + wn * 64 + (l & 15);
#pragma unroll
  for (int i = 0; i < 8; ++i) {
#pragma unroll
    for (int j = 0; j < 4; ++j) {
#pragma unroll
      for (int r = 0; r < 4; ++r) {
        const int mm = m0 + mb + i * 16 + r;
        if (mm < count) {
          const int nn = nb + j * 16;
          if (MODE == 0) {
            C[(size_t)(seg + mm) * N + nn] = acc[i][j][r];
          } else {
            C[(size_t)pt[seg + mm] * N + nn] = acc[i][j][r];
          }
        }
      }
    }
  }
}

// ---------------- out[t] = ybuf[2t] + ybuf[2t+1] ----------------
__global__ __launch_bounds__(256) void k_combine(const float4* __restrict__ y,
                                                 float4* __restrict__ out) {
  const int t = blockIdx.x;                       // token
  const float4* y0 = y + (size_t)(2 * t) * (HIDDEN / 4);
  const float4* y1 = y + (size_t)(2 * t + 1) * (HIDDEN / 4);
  float4* o = out + (size_t)t * (HIDDEN / 4);
#pragma unroll
  for (int q = 0; q < 2; ++q) {
    const int c = threadIdx.x + q * 256;          // 512 float4 per token
    const float4 a = y0[c], b = y1[c];
    o[c] = make_float4(a.x + b.x, a.y + b.y, a.z + b.z, a.w + b.w);
  }
}

// ---------------- launch ----------------
extern "C" void kernel_launch(void* const* d_in, const int* in_sizes, int n_in,
                              void* d_out, int out_size, void* d_ws, size_t ws_size,
                              hipStream_t stream) {
  const float* hs  = (const float*)d_in[0];
  const int*   tki = (const int*)d_in[1];
  const float* tkw = (const float*)d_in[2];
  const float* guw = (const float*)d_in[3];
  const float* dww = (const float*)d_in[4];
  const int*   gupr= (const int*)d_in[5];
  const float* gua = (const float*)d_in[6];
  const int*   dwp = (const int*)d_in[7];
  const float* dwa = (const float*)d_in[8];
  const float* gus = (const float*)d_in[9];
  const float* dwsc= (const float*)d_in[10];
  float* out = (float*)d_out;
  char* ws = (char*)d_ws;

  unsigned short* gup_bf = (unsigned short*)(ws + 0);          //  50,331,648 B
  unsigned short* dwn_bf = (unsigned short*)(ws + 50331648);   //  25,165,824 B
  unsigned short* x_bf   = (unsigned short*)(ws + 75497472);   //  16,777,216 B
  float*          hbuf   = (float*)(ws + 92274688);            //  50,331,648 B
  unsigned short* interb = (unsigned short*)(ws + 142606336);  //  12,582,912 B
  // ybuf (8192 x 2048 f32 = 67,108,864 B) reuses x_bf + hbuf (both dead after k_silu2)
  float*          ybuf   = (float*)(ws + 75497472);
  int*            pt     = (int*)(ws + 155189248);             //  32,768 B
  float*          pw     = (float*)(ws + 155222016);           //  32,768 B
  int*            cnt    = (int*)(ws + 155254784);             //  cnt/off/cur/tmap/nv (<4 KiB)
  int*            off    = cnt + 8;
  int*            cur    = cnt + 16;
  int*            tmap   = cnt + 24;
  int*            nv     = cnt + 120;
  float4*         tg     = (float4*)(ws + 155258880);          // 131,072 B (16 grp)
  float4*         td     = (float4*)(ws + 155389952);          //  49,152 B (6 grp)
  float*          grch   = (float*)(ws + 155439104);           //   8,192 B
  float*          drch   = (float*)(ws + 155447296);           //   3,072 B

  (void)hipMemsetAsync(cnt, 0, 32, stream);

  k_hist<<<32, 256, 0, stream>>>(tki, cnt);
  k_scan<<<1, 64, 0, stream>>>(cnt, off, cur, tmap, nv);
  k_scatter<<<32, 256, 0, stream>>>(tki, tkw, off, cur, pt, pw);
  k_tbl<<<16, 256, 0, stream>>>(gupr, gua, dwp, dwa, gus, dwsc, tg, td, grch, drch);
  k_rotx<<<4096, 256, 0, stream>>>(hs, grch, tg, x_bf);
  k_quant<<<12288, 256, 0, stream>>>(guw, tg, gus, gup_bf, HIDDEN, 16);
  k_quant<<<6144, 256, 0, stream>>>(dww, td, dwsc, dwn_bf, INTERM, 6);
  k_gemm<0><<<dim3(6, MAXT), 512, 0, stream>>>(x_bf, gup_bf, hbuf, pt, off, cnt, tmap, nv);
  k_silu2<<<3072, 256, 0, stream>>>(hbuf, pw, drch, td, interb);
  k_gemm<1><<<dim3(8, MAXT), 512, 0, stream>>>(interb, dwn_bf, ybuf, pt, off, cnt, tmap, nv);
  k_combine<<<T_TOKENS, 256, 0, stream>>>((const float4*)ybuf, (float4*)out);
}

// Round 6
// 519.127 us; speedup vs baseline: 1.0761x; 1.0369x over previous
//
#include <hip/hip_runtime.h>

#define T_TOKENS 4096
#define HIDDEN   2048
#define INTERM   768
#define NE       8
#define NPAIR    8192   // T_TOKENS * TOP_K
#define NROT     4
#define MAXT     40     // max total 256-row m-tiles across experts (32 + 8)

typedef __bf16 bf16x8 __attribute__((ext_vector_type(8)));
typedef float  f32x4  __attribute__((ext_vector_type(4)));

__device__ __forceinline__ unsigned short f2bf(float f) {
  unsigned u = __float_as_uint(f);
  u += 0x7fffu + ((u >> 16) & 1u);   // round-to-nearest-even (finite inputs only)
  return (unsigned short)(u >> 16);
}

__device__ __forceinline__ void async16(const void* g, void* l) {
  __builtin_amdgcn_global_load_lds((const __attribute__((address_space(1))) void*)g,
                                   (__attribute__((address_space(3))) void*)l, 16, 0, 0);
}

// ---------------- routing: histogram / scan+tilemap / scatter ----------------
__global__ void k_hist(const int* __restrict__ idx, int* __restrict__ cnt) {
  const int t = blockIdx.x * 256 + threadIdx.x;
  if (t < NPAIR) atomicAdd(&cnt[idx[t]], 1);
}

__global__ void k_scan(const int* __restrict__ cnt, int* __restrict__ off,
                       int* __restrict__ cur, int* __restrict__ tmap,
                       int* __restrict__ nv) {
  if (threadIdx.x == 0) {
    int a = 0, tt = 0;
    for (int e = 0; e < NE; ++e) {
      off[e] = a; cur[e] = 0;
      const int c = cnt[e];
      for (int m = 0; m < c; m += 256) tmap[tt++] = (e << 16) | (m >> 8);
      a += c;
    }
    nv[0] = tt;                      // number of VALID 256-row m-tiles
    for (; tt < MAXT; ++tt) tmap[tt] = -1;
  }
}

// pt[pos] = ORIGINAL pair index t (token = t>>1, slot = t&1)
__global__ void k_scatter(const int* __restrict__ idx, const float* __restrict__ wts,
                          const int* __restrict__ off, int* __restrict__ cur,
                          int* __restrict__ pt, float* __restrict__ pw) {
  const int t = blockIdx.x * 256 + threadIdx.x;
  if (t < NPAIR) {
    const int e = idx[t];
    const int pos = off[e] + atomicAdd(&cur[e], 1);
    pt[pos] = t;          // pair id (carries token and slot)
    pw[pos] = wts[t];     // routing weight
  }
}

// ---------------- build per-destination rotation tables + recip channel scales ----
// entry (group g, rot r, dest d): {cos, signed_sin, partner, 0};
// forward: new[d] = cos*old[d] + signed_sin*old[partner]
__global__ void k_tbl(const int* __restrict__ gp, const float* __restrict__ ga,
                      const int* __restrict__ dp, const float* __restrict__ da,
                      const float* __restrict__ gch, const float* __restrict__ dch,
                      float4* __restrict__ tg, float4* __restrict__ td,
                      float* __restrict__ grch, float* __restrict__ drch) {
  const int t = blockIdx.x * 256 + threadIdx.x;
  if (t < NROT * (HIDDEN / 2)) {
    const int r = t >> 10, s = t & 1023;          // slot s over 1024 pairs
    const int grp = s >> 6;
    const int i = gp[r * HIDDEN + 2 * s], j = gp[r * HIDDEN + 2 * s + 1];
    const float a = ga[r * (HIDDEN / 2) + s];
    const float c = cosf(a), sn = sinf(a);
    tg[(grp * NROT + r) * 128 + i] = make_float4(c, -sn, __int_as_float(j), 0.f);
    tg[(grp * NROT + r) * 128 + j] = make_float4(c,  sn, __int_as_float(i), 0.f);
  }
  if (t < NROT * (INTERM / 2)) {
    const int r = t / (INTERM / 2), s = t - r * (INTERM / 2);
    const int grp = s >> 6;
    const int i = dp[r * INTERM + 2 * s], j = dp[r * INTERM + 2 * s + 1];
    const float a = da[r * (INTERM / 2) + s];
    const float c = cosf(a), sn = sinf(a);
    td[(grp * NROT + r) * 128 + i] = make_float4(c, -sn, __int_as_float(j), 0.f);
    td[(grp * NROT + r) * 128 + j] = make_float4(c,  sn, __int_as_float(i), 0.f);
  }
  if (t < HIDDEN) grch[t] = 1.0f / gch[t];
  if (t < INTERM) drch[t] = 1.0f / dch[t];
}

// helper: 4 forward rotation passes on (v0,v1) held across the wave (128-group)
#define FWD_ROT(tl, v0, v1)                                                     \
  _Pragma("unroll")                                                             \
  for (int r = 0; r < NROT; ++r) {                                              \
    const float4 e0 = tl[r * 128 + l];                                          \
    const float4 e1 = tl[r * 128 + 64 + l];                                     \
    const int p0 = __float_as_int(e0.z), p1 = __float_as_int(e1.z);             \
    const int a0 = (p0 & 63) << 2, a1 = (p1 & 63) << 2;                         \
    _Pragma("unroll")                                                           \
    for (int q = 0; q < 4; ++q) {                                               \
      const int x0 = __float_as_int(v0[q]), x1 = __float_as_int(v1[q]);         \
      const float lo0 = __int_as_float(__builtin_amdgcn_ds_bpermute(a0, x0));   \
      const float hi0 = __int_as_float(__builtin_amdgcn_ds_bpermute(a0, x1));   \
      const float lo1 = __int_as_float(__builtin_amdgcn_ds_bpermute(a1, x0));   \
      const float hi1 = __int_as_float(__builtin_amdgcn_ds_bpermute(a1, x1));   \
      const float op0 = (p0 & 64) ? hi0 : lo0;                                  \
      const float op1 = (p1 & 64) ? hi1 : lo1;                                  \
      {                                                                         \
        _Pragma("clang fp contract(off)")                                       \
        v0[q] = e0.x * v0[q] + e0.y * op0;                                      \
        v1[q] = e1.x * v1[q] + e1.y * op1;                                      \
      }                                                                         \
    }                                                                           \
  }

// ---------------- weight pseudo-quantize (forward only, outputs rotated q) ------
__global__ __launch_bounds__(256) void k_quant(
    const float* __restrict__ W, const float4* __restrict__ tbl,
    const float* __restrict__ ch, unsigned short* __restrict__ out, int In, int G) {
  __shared__ float4 tl[NROT * 128];
  const int wv = threadIdx.x >> 6, l = threadIdx.x & 63;
  const int g = blockIdx.x % G;
  const int rowblk = blockIdx.x / G;
  const int row0 = rowblk * 16 + wv * 4;
  const int colbase = g << 7;
  tl[threadIdx.x]       = tbl[(size_t)g * NROT * 128 + threadIdx.x];
  tl[256 + threadIdx.x] = tbl[(size_t)g * NROT * 128 + 256 + threadIdx.x];
  __syncthreads();
  const float c0 = ch[colbase + l], c1 = ch[colbase + 64 + l];
  float v0[4], v1[4];
#pragma unroll
  for (int q = 0; q < 4; ++q) {
#pragma clang fp contract(off)
    const float* Wr = W + (size_t)(row0 + q) * In + colbase;
    v0[q] = Wr[l] * c0;
    v1[q] = Wr[64 + l] * c1;
  }
  FWD_ROT(tl, v0, v1)
  // fake quant per row; output stays in rotated space
#pragma unroll
  for (int q = 0; q < 4; ++q) {
    float mn = fminf(v0[q], v1[q]), mx = fmaxf(v0[q], v1[q]);
#pragma unroll
    for (int o = 32; o > 0; o >>= 1) {
      mn = fminf(mn, __shfl_xor(mn, o));
      mx = fmaxf(mx, __shfl_xor(mx, o));
    }
    {
#pragma clang fp contract(off)
      const float scale = fmaxf(mx - mn, 1e-5f) / 15.0f;
      const float zero = rintf(-mn / scale);
      const float q0 = fminf(fmaxf(rintf(v0[q] / scale) + zero, 0.0f), 15.0f);
      const float q1 = fminf(fmaxf(rintf(v1[q] / scale) + zero, 0.0f), 15.0f);
      v0[q] = (q0 - zero) * scale;
      v1[q] = (q1 - zero) * scale;
    }
  }
#pragma unroll
  for (int q = 0; q < 4; ++q) {
    unsigned short* Or = out + (size_t)(row0 + q) * In + colbase;
    Or[l]      = f2bf(v0[q]);
    Or[64 + l] = f2bf(v1[q]);
  }
}

// ---------------- x' = R(x / ch) -> bf16 ----------------
__global__ __launch_bounds__(256) void k_rotx(
    const float* __restrict__ X, const float* __restrict__ rch,
    const float4* __restrict__ tbl, unsigned short* __restrict__ out) {
  __shared__ float4 tl[NROT * 128];
  const int wv = threadIdx.x >> 6, l = threadIdx.x & 63;
  const int g = blockIdx.x % 16;                 // HIDDEN/128 groups
  const int rowblk = blockIdx.x / 16;
  const int row0 = rowblk * 16 + wv * 4;
  const int colbase = g << 7;
  tl[threadIdx.x]       = tbl[(size_t)g * NROT * 128 + threadIdx.x];
  tl[256 + threadIdx.x] = tbl[(size_t)g * NROT * 128 + 256 + threadIdx.x];
  __syncthreads();
  const float i0 = rch[colbase + l], i1 = rch[colbase + 64 + l];
  float v0[4], v1[4];
#pragma unroll
  for (int q = 0; q < 4; ++q) {
    const float* Xr = X + (size_t)(row0 + q) * HIDDEN + colbase;
    v0[q] = Xr[l] * i0;
    v1[q] = Xr[64 + l] * i1;
  }
  FWD_ROT(tl, v0, v1)
#pragma unroll
  for (int q = 0; q < 4; ++q) {
    unsigned short* Or = out + (size_t)(row0 + q) * HIDDEN + colbase;
    Or[l]      = f2bf(v0[q]);
    Or[64 + l] = f2bf(v1[q]);
  }
}

// ---------------- inter' = R_d( silu(gate)*up*wgt / ch_d ) -> bf16 ----------------
__global__ __launch_bounds__(256) void k_silu2(
    const float* __restrict__ h, const float* __restrict__ pw,
    const float* __restrict__ rch, const float4* __restrict__ tbl,
    unsigned short* __restrict__ out) {
  __shared__ float4 tl[NROT * 128];
  const int wv = threadIdx.x >> 6, l = threadIdx.x & 63;
  const int g = blockIdx.x % 6;                  // INTERM/128 groups
  const int rowblk = blockIdx.x / 6;
  const int row0 = rowblk * 16 + wv * 4;
  const int colbase = g << 7;
  tl[threadIdx.x]       = tbl[(size_t)g * NROT * 128 + threadIdx.x];
  tl[256 + threadIdx.x] = tbl[(size_t)g * NROT * 128 + 256 + threadIdx.x];
  __syncthreads();
  const float i0 = rch[colbase + l], i1 = rch[colbase + 64 + l];
  float v0[4], v1[4];
#pragma unroll
  for (int q = 0; q < 4; ++q) {
    const int row = row0 + q;
    const float wgt = pw[row];
    const float* hr = h + (size_t)row * 1536 + colbase;
    const float g0 = hr[l], g1 = hr[64 + l];
    const float u0 = hr[768 + l], u1 = hr[768 + 64 + l];
    v0[q] = g0 / (1.0f + expf(-g0)) * u0 * wgt * i0;
    v1[q] = g1 / (1.0f + expf(-g1)) * u1 * wgt * i1;
  }
  FWD_ROT(tl, v0, v1)
#pragma unroll
  for (int q = 0; q < 4; ++q) {
    unsigned short* Or = out + (size_t)(row0 + q) * INTERM + colbase;
    Or[l]      = f2bf(v0[q]);
    Or[64 + l] = f2bf(v1[q]);
  }
}

// ---------------- gate-up GEMM (MODE 0 only): C = A * B^T ----------------
// 256x256 tile, BK=64, 8 waves (2x4), 8-phase schedule, counted vmcnt(4),
// raw s_barrier pairs, setprio around MFMA, conflict-free both-sides swizzle.
template <int MODE>
__launch_bounds__(512, 2)
__global__ void k_gemm(const unsigned short* __restrict__ A,
                       const unsigned short* __restrict__ Bw,
                       float* __restrict__ C,
                       const int* __restrict__ pt,
                       const int* __restrict__ off,
                       const int* __restrict__ cnt,
                       const int* __restrict__ tmap,
                       const int* __restrict__ nv) {
  constexpr int K = MODE ? INTERM : HIDDEN;
  constexpr int N = MODE ? HIDDEN : 2 * INTERM;
  constexpr int XW = MODE ? 8 : 6;            // n-tiles of 256
  constexpr int NT = K / 64;                  // K-tiles

  const int hw  = blockIdx.x + XW * blockIdx.y;
  const int xcd = hw & 7;
  const int pos = hw >> 3;
  const int nvalid = nv[0];
  const int q8 = nvalid >> 3, r8 = nvalid & 7;
  const int rs = q8 + (xcd < r8 ? 1 : 0);
  const int y0 = xcd * q8 + (xcd < r8 ? xcd : r8);
  if (pos >= rs * XW) return;
  const int xg = pos % XW;
  const int yg = y0 + pos / XW;
  const int tm = tmap[yg];
  if (tm < 0) return;
  const int e = tm >> 16;
  const int m0 = (tm & 0xffff) << 8;
  const int count = cnt[e];
  const int seg = off[e];
  const int n0 = xg * 256;
  const unsigned short* Be = Bw + (size_t)e * N * K;

  __shared__ unsigned short lds[65536];       // 128 KiB

  const int tid = threadIdx.x;
  const int w = tid >> 6, l = tid & 63;
  const int wm = w >> 2, wn = w & 3;
  const int w512 = w * 512;

  // ---- stage source pointers (pre-swizzled chunk: c ^ ((row>>1)&3)) ----
  const int sr = tid >> 2;                              // stage row 0..127
  const int cs = (((tid & 3) ^ ((tid >> 3) & 3))) * 8;  // element offset of 16B chunk
  int pA0 = m0 + sr;        if (pA0 > count - 1) pA0 = count - 1;
  int pA1 = m0 + sr + 128;  if (pA1 > count - 1) pA1 = count - 1;
  size_t arow0, arow1;
  if (MODE == 0) { arow0 = (size_t)(pt[seg + pA0] >> 1); arow1 = (size_t)(pt[seg + pA1] >> 1); }
  else           { arow0 = (size_t)(seg + pA0); arow1 = (size_t)(seg + pA1); }
  const unsigned short* paS0 = A + arow0 * K + cs;
  const unsigned short* paS1 = A + arow1 * K + cs;
  const unsigned short* pbS0 = Be + (size_t)(n0 + sr) * K + cs;
  const unsigned short* pbS1 = Be + (size_t)(n0 + sr + 128) * K + cs;

  // ---- fragment read offsets (same XOR: q ^ ((row>>1)&3), row%16 = l&15) ----
  const int cswz  = ((l >> 4) ^ (((l & 15) >> 1) & 3)) * 8;
  const int abase = (wm * 128 + (l & 15)) * 32 + cswz;            // within A ksub half
  const int bbase = (wn * 64  + (l & 15)) * 32 + cswz + 16384;    // +B offset folded

  f32x4 acc[8][4];
#pragma unroll
  for (int i = 0; i < 8; ++i)
#pragma unroll
    for (int j = 0; j < 4; ++j) acc[i][j] = (f32x4)0.0f;

  // layout (ushort units): buf*32768 + {A:0,B:16384} + ksub*8192 + row*32 + chunk*8
#define STG_A(dst, koff) do { \
    async16(paS0 + (koff), &lds[(dst) + w512]); \
    async16(paS1 + (koff), &lds[(dst) + 4096 + w512]); } while (0)
#define STG_B(dst, koff) do { \
    async16(pbS0 + (koff), &lds[(dst) + w512]); \
    async16(pbS1 + (koff), &lds[(dst) + 4096 + w512]); } while (0)

  // prologue: t0 fully + t1 kh0   (12 vmem instr; newest 4 = t1 kh0 stay in flight)
  STG_A(0,     0);  STG_B(16384,       0);
  STG_A(8192,  32); STG_B(16384+8192,  32);
  STG_A(32768, 64); STG_B(32768+16384, 64);
  asm volatile("s_waitcnt vmcnt(4)" ::: "memory");
  __builtin_amdgcn_s_barrier();

  for (int t = 0; t < NT; ++t) {
    const int base = (t & 1) << 15;            // 0 / 32768
    const int alt  = base ^ 32768;
    const int k1 = (t + 1) * 64, k2 = (t + 2) * 64;
    bf16x8 a[4], bq[4];

    // ---------------- phase 1: ksub0, m-half0 (+B ksub0) ----------------
#pragma unroll
    for (int ii = 0; ii < 4; ++ii) a[ii]  = *(const bf16x8*)&lds[base + abase + ii * 512];
#pragma unroll
    for (int j = 0; j < 4; ++j)    bq[j]  = *(const bf16x8*)&lds[base + bbase + j * 512];
    if (t + 1 < NT) STG_A(alt + 8192, k1 + 32);            // A-kh1(t+1) -> idle buf
    __builtin_amdgcn_s_barrier();
    asm volatile("s_waitcnt lgkmcnt(0)" ::: "memory");
    __builtin_amdgcn_sched_barrier(0);
    __builtin_amdgcn_s_setprio(1);
#pragma unroll
    for (int ii = 0; ii < 4; ++ii)
#pragma unroll
      for (int j = 0; j < 4; ++j)
        acc[ii][j] = __builtin_amdgcn_mfma_f32_16x16x32_bf16(a[ii], bq[j], acc[ii][j], 0, 0, 0);
    __builtin_amdgcn_s_setprio(0);
    __builtin_amdgcn_s_barrier();

    // ---------------- phase 2: ksub0, m-half1 ----------------
#pragma unroll
    for (int ii = 0; ii < 4; ++ii) a[ii] = *(const bf16x8*)&lds[base + abase + (4 + ii) * 512];
    if (t + 1 < NT) STG_B(alt + 16384 + 8192, k1 + 32);    // B-kh1(t+1) -> idle buf
    __builtin_amdgcn_s_barrier();
    asm volatile("s_waitcnt lgkmcnt(0)" ::: "memory");
    __builtin_amdgcn_sched_barrier(0);
    __builtin_amdgcn_s_setprio(1);
#pragma unroll
    for (int ii = 0; ii < 4; ++ii)
#pragma unroll
      for (int j = 0; j < 4; ++j)
        acc[4 + ii][j] = __builtin_amdgcn_mfma_f32_16x16x32_bf16(a[ii], bq[j], acc[4 + ii][j], 0, 0, 0);
    __builtin_amdgcn_s_setprio(0);
    __builtin_amdgcn_s_barrier();

    // ---------------- phase 3: ksub1, m-half0 (+B ksub1) ----------------
#pragma unroll
    for (int ii = 0; ii < 4; ++ii) a[ii] = *(const bf16x8*)&lds[base + 8192 + abase + ii * 512];
#pragma unroll
    for (int j = 0; j < 4; ++j)    bq[j] = *(const bf16x8*)&lds[base + 8192 + bbase + j * 512];
    if (t + 2 < NT) STG_A(base, k2);                       // A-kh0(t+2) -> cur buf (kh0 free)
    __builtin_amdgcn_s_barrier();
    asm volatile("s_waitcnt lgkmcnt(0)" ::: "memory");
    __builtin_amdgcn_sched_barrier(0);
    __builtin_amdgcn_s_setprio(1);
#pragma unroll
    for (int ii = 0; ii < 4; ++ii)
#pragma unroll
      for (int j = 0; j < 4; ++j)
        acc[ii][j] = __builtin_amdgcn_mfma_f32_16x16x32_bf16(a[ii], bq[j], acc[ii][j], 0, 0, 0);
    __builtin_amdgcn_s_setprio(0);
    __builtin_amdgcn_s_barrier();

    // ---------------- phase 4: ksub1, m-half1 ----------------
#pragma unroll
    for (int ii = 0; ii < 4; ++ii) a[ii] = *(const bf16x8*)&lds[base + 8192 + abase + (4 + ii) * 512];
    if (t + 2 < NT) STG_B(base + 16384, k2);               // B-kh0(t+2) -> cur buf
    __builtin_amdgcn_s_barrier();
    asm volatile("s_waitcnt lgkmcnt(0)" ::: "memory");
    __builtin_amdgcn_sched_barrier(0);
    __builtin_amdgcn_s_setprio(1);
#pragma unroll
    for (int ii = 0; ii < 4; ++ii)
#pragma unroll
      for (int j = 0; j < 4; ++j)
        acc[4 + ii][j] = __builtin_amdgcn_mfma_f32_16x16x32_bf16(a[ii], bq[j], acc[4 + ii][j], 0, 0, 0);
    __builtin_amdgcn_s_setprio(0);
    if (t + 1 < NT) {                       // tile boundary: counted vmcnt (T4)
      if (t + 1 == NT - 1) asm volatile("s_waitcnt vmcnt(0)" ::: "memory");
      else                 asm volatile("s_waitcnt vmcnt(4)" ::: "memory");
    }
    __builtin_amdgcn_s_barrier();
  }
#undef STG_A
#undef STG_B

  // ---------------- epilogue ----------------
  const int mb = wm * 128 + (l >> 4) * 4;
  const int nb = n0 + wn * 64 + (l & 15);
#pragma unroll
  for (int i = 0; i < 8; ++i) {
#pragma unroll
    for (int j = 0; j < 4; ++j) {
#pragma unroll
      for (int r = 0; r < 4; ++r) {
        const int mm = m0 + mb + i * 16 + r;
        if (mm < count) {
          const int nn = nb + j * 16;
          if (MODE == 0) {
            C[(size_t)(seg + mm) * N + nn] = acc[i][j][r];
          } else {
            C[(size_t)pt[seg + mm] * N + nn] = acc[i][j][r];
          }
        }
      }
    }
  }
}

// ---------------- down GEMM: 256x128 tile, BK=32, 2 blocks/CU, 2-phase ----------
// M tiny-K GEMM is tail-bound at 256x256/1-block-per-CU (288 blocks -> 2 rounds,
// MfmaUtil 11%). Here: 576 finer blocks, acc[4][4] (64 regs, launch_bounds(512,4)
// -> <=128 VGPR -> 4 waves/SIMD), LDS 48KB -> 2 blocks/CU co-resident; the
// co-resident block covers the __syncthreads vmcnt drain (m114/m230 overlap).
// K-loop = R2's proven 2-phase pattern (no inline asm). Same both-sides swizzle.
__launch_bounds__(512, 4)
__global__ void k_gemm1(const unsigned short* __restrict__ A,
                        const unsigned short* __restrict__ Bw,
                        float* __restrict__ C,
                        const int* __restrict__ pt,
                        const int* __restrict__ off,
                        const int* __restrict__ cnt,
                        const int* __restrict__ tmap,
                        const int* __restrict__ nv) {
  constexpr int K = INTERM;                 // 768
  constexpr int N = HIDDEN;                 // 2048
  constexpr int XW = 16;                    // n-tiles of 128
  constexpr int NT = K / 32;                // 24 K-tiles

  const int hw  = blockIdx.x + XW * blockIdx.y;
  const int xcd = hw & 7;
  const int pos = hw >> 3;
  const int nvalid = nv[0];
  const int q8 = nvalid >> 3, r8 = nvalid & 7;
  const int rs = q8 + (xcd < r8 ? 1 : 0);
  const int y0 = xcd * q8 + (xcd < r8 ? xcd : r8);
  if (pos >= rs * XW) return;
  const int xg = pos % XW;
  const int yg = y0 + pos / XW;
  const int tm = tmap[yg];
  if (tm < 0) return;
  const int e = tm >> 16;
  const int m0 = (tm & 0xffff) << 8;
  const int count = cnt[e];
  const int seg = off[e];
  const int n0 = xg * 128;
  const unsigned short* Be = Bw + (size_t)e * N * K;

  __shared__ unsigned short lds[24576];     // 48 KiB: [2][A:8192 | B:4096] ushort

  const int tid = threadIdx.x;
  const int w = tid >> 6, l = tid & 63;
  const int wm = w >> 1, wn = w & 1;        // 4m x 2n waves, wave-tile 64x64
  const int w512 = w * 512;

  // stage: A rows sr, sr+128 (2 chunks/thread), B row sr (1 chunk/thread)
  const int sr = tid >> 2;
  const int cs = ((tid & 3) ^ ((tid >> 3) & 3)) * 8;   // pre-swizzled source chunk
  int pA0 = m0 + sr;        if (pA0 > count - 1) pA0 = count - 1;
  int pA1 = m0 + sr + 128;  if (pA1 > count - 1) pA1 = count - 1;
  const unsigned short* paS0 = A + (size_t)(seg + pA0) * K + cs;
  const unsigned short* paS1 = A + (size_t)(seg + pA1) * K + cs;
  const unsigned short* pbS0 = Be + (size_t)(n0 + sr) * K + cs;

  // fragment reads (same XOR involution on the read side)
  const int cswz  = ((l >> 4) ^ (((l & 15) >> 1) & 3)) * 8;
  const int abase = (wm * 64 + (l & 15)) * 32 + cswz;
  const int bbase = 8192 + (wn * 64 + (l & 15)) * 32 + cswz;

  f32x4 acc[4][4];
#pragma unroll
  for (int i = 0; i < 4; ++i)
#pragma unroll
    for (int j = 0; j < 4; ++j) acc[i][j] = (f32x4)0.0f;

  // layout (ushort): buf*12288 + {A: row*32 (rows 0..255), B: 8192 + row*32}
#define STG1(b, koff) do {                                   \
    async16(paS0 + (koff), &lds[(b) * 12288 + w512]);        \
    async16(paS1 + (koff), &lds[(b) * 12288 + 4096 + w512]); \
    async16(pbS0 + (koff), &lds[(b) * 12288 + 8192 + w512]); \
  } while (0)

  STG1(0, 0);                               // tile 0
  int buf = 0;
  for (int t = 0; t < NT; ++t) {
    __syncthreads();                        // vmcnt(0)+lgkmcnt(0)+barrier: tile t ready
    if (t + 1 < NT) STG1(buf ^ 1, (t + 1) * 32);
    const int lb = buf * 12288;
    bf16x8 a[4], bq[4];
#pragma unroll
    for (int i = 0; i < 4; ++i) a[i]  = *(const bf16x8*)&lds[lb + abase + i * 512];
#pragma unroll
    for (int j = 0; j < 4; ++j) bq[j] = *(const bf16x8*)&lds[lb + bbase + j * 512];
#pragma unroll
    for (int i = 0; i < 4; ++i)
#pragma unroll
      for (int j = 0; j < 4; ++j)
        acc[i][j] = __builtin_amdgcn_mfma_f32_16x16x32_bf16(a[i], bq[j], acc[i][j], 0, 0, 0);
    buf ^= 1;
  }
#undef STG1

  const int mb = wm * 64 + (l >> 4) * 4;
  const int nb = n0 + wn * 64 + (l & 15);
#pragma unroll
  for (int i = 0; i < 4; ++i) {
#pragma unroll
    for (int j = 0; j < 4; ++j) {
#pragma unroll
      for (int r = 0; r < 4; ++r) {
        const int mm = m0 + mb + i * 16 + r;
        if (mm < count) {
          C[(size_t)pt[seg + mm] * N + nb + j * 16] = acc[i][j][r];
        }
      }
    }
  }
}

// ---------------- out[t] = ybuf[2t] + ybuf[2t+1] ----------------
__global__ __launch_bounds__(256) void k_combine(const float4* __restrict__ y,
                                                 float4* __restrict__ out) {
  const int t = blockIdx.x;                       // token
  const float4* y0 = y + (size_t)(2 * t) * (HIDDEN / 4);
  const float4* y1 = y + (size_t)(2 * t + 1) * (HIDDEN / 4);
  float4* o = out + (size_t)t * (HIDDEN / 4);
#pragma unroll
  for (int q = 0; q < 2; ++q) {
    const int c = threadIdx.x + q * 256;          // 512 float4 per token
    const float4 a = y0[c], b = y1[c];
    o[c] = make_float4(a.x + b.x, a.y + b.y, a.z + b.z, a.w + b.w);
  }
}

// ---------------- launch ----------------
extern "C" void kernel_launch(void* const* d_in, const int* in_sizes, int n_in,
                              void* d_out, int out_size, void* d_ws, size_t ws_size,
                              hipStream_t stream) {
  const float* hs  = (const float*)d_in[0];
  const int*   tki = (const int*)d_in[1];
  const float* tkw = (const float*)d_in[2];
  const float* guw = (const float*)d_in[3];
  const float* dww = (const float*)d_in[4];
  const int*   gupr= (const int*)d_in[5];
  const float* gua = (const float*)d_in[6];
  const int*   dwp = (const int*)d_in[7];
  const float* dwa = (const float*)d_in[8];
  const float* gus = (const float*)d_in[9];
  const float* dwsc= (const float*)d_in[10];
  float* out = (float*)d_out;
  char* ws = (char*)d_ws;

  unsigned short* gup_bf = (unsigned short*)(ws + 0);          //  50,331,648 B
  unsigned short* dwn_bf = (unsigned short*)(ws + 50331648);   //  25,165,824 B
  unsigned short* x_bf   = (unsigned short*)(ws + 75497472);   //  16,777,216 B
  float*          hbuf   = (float*)(ws + 92274688);            //  50,331,648 B
  unsigned short* interb = (unsigned short*)(ws + 142606336);  //  12,582,912 B
  // ybuf (8192 x 2048 f32 = 67,108,864 B) reuses x_bf + hbuf (both dead after k_silu2)
  float*          ybuf   = (float*)(ws + 75497472);
  int*            pt     = (int*)(ws + 155189248);             //  32,768 B
  float*          pw     = (float*)(ws + 155222016);           //  32,768 B
  int*            cnt    = (int*)(ws + 155254784);             //  cnt/off/cur/tmap/nv (<4 KiB)
  int*            off    = cnt + 8;
  int*            cur    = cnt + 16;
  int*            tmap   = cnt + 24;
  int*            nv     = cnt + 120;
  float4*         tg     = (float4*)(ws + 155258880);          // 131,072 B (16 grp)
  float4*         td     = (float4*)(ws + 155389952);          //  49,152 B (6 grp)
  float*          grch   = (float*)(ws + 155439104);           //   8,192 B
  float*          drch   = (float*)(ws + 155447296);           //   3,072 B

  (void)hipMemsetAsync(cnt, 0, 32, stream);

  k_hist<<<32, 256, 0, stream>>>(tki, cnt);
  k_scan<<<1, 64, 0, stream>>>(cnt, off, cur, tmap, nv);
  k_scatter<<<32, 256, 0, stream>>>(tki, tkw, off, cur, pt, pw);
  k_tbl<<<16, 256, 0, stream>>>(gupr, gua, dwp, dwa, gus, dwsc, tg, td, grch, drch);
  k_rotx<<<4096, 256, 0, stream>>>(hs, grch, tg, x_bf);
  k_quant<<<12288, 256, 0, stream>>>(guw, tg, gus, gup_bf, HIDDEN, 16);
  k_quant<<<6144, 256, 0, stream>>>(dww, td, dwsc, dwn_bf, INTERM, 6);
  k_gemm<0><<<dim3(6, MAXT), 512, 0, stream>>>(x_bf, gup_bf, hbuf, pt, off, cnt, tmap, nv);
  k_silu2<<<3072, 256, 0, stream>>>(hbuf, pw, drch, td, interb);
  k_gemm1<<<dim3(16, MAXT), 512, 0, stream>>>(interb, dwn_bf, ybuf, pt, off, cnt, tmap, nv);
  k_combine<<<T_TOKENS, 256, 0, stream>>>((const float4*)ybuf, (float4*)out);
}

// Round 9
// 509.234 us; speedup vs baseline: 1.0970x; 1.0194x over previous
//
#include <hip/hip_runtime.h>

#define T_TOKENS 4096
#define HIDDEN   2048
#define INTERM   768
#define NE       8
#define NPAIR    8192   // T_TOKENS * TOP_K
#define NROT     4
#define MAXT     40     // max total 256-row m-tiles across experts (32 + 8)

typedef __bf16 bf16x8 __attribute__((ext_vector_type(8)));
typedef float  f32x4  __attribute__((ext_vector_type(4)));

__device__ __forceinline__ unsigned short f2bf(float f) {
  unsigned u = __float_as_uint(f);
  u += 0x7fffu + ((u >> 16) & 1u);   // round-to-nearest-even (finite inputs only)
  return (unsigned short)(u >> 16);
}

__device__ __forceinline__ void async16(const void* g, void* l) {
  __builtin_amdgcn_global_load_lds((const __attribute__((address_space(1))) void*)g,
                                   (__attribute__((address_space(3))) void*)l, 16, 0, 0);
}

// ---------------- routing: histogram / scan+tilemap / scatter ----------------
__global__ void k_hist(const int* __restrict__ idx, int* __restrict__ cnt) {
  const int t = blockIdx.x * 256 + threadIdx.x;
  if (t < NPAIR) atomicAdd(&cnt[idx[t]], 1);
}

__global__ void k_scan(const int* __restrict__ cnt, int* __restrict__ off,
                       int* __restrict__ cur, int* __restrict__ tmap,
                       int* __restrict__ nv) {
  if (threadIdx.x == 0) {
    int a = 0, tt = 0;
    for (int e = 0; e < NE; ++e) {
      off[e] = a; cur[e] = 0;
      const int c = cnt[e];
      for (int m = 0; m < c; m += 256) tmap[tt++] = (e << 16) | (m >> 8);
      a += c;
    }
    nv[0] = tt;                      // number of VALID 256-row m-tiles
    for (; tt < MAXT; ++tt) tmap[tt] = -1;
  }
}

// pt[pos] = ORIGINAL pair index t (token = t>>1, slot = t&1)
__global__ void k_scatter(const int* __restrict__ idx, const float* __restrict__ wts,
                          const int* __restrict__ off, int* __restrict__ cur,
                          int* __restrict__ pt, float* __restrict__ pw) {
  const int t = blockIdx.x * 256 + threadIdx.x;
  if (t < NPAIR) {
    const int e = idx[t];
    const int pos = off[e] + atomicAdd(&cur[e], 1);
    pt[pos] = t;          // pair id (carries token and slot)
    pw[pos] = wts[t];     // routing weight
  }
}

// ---------------- build per-destination rotation tables + recip channel scales ----
// entry (group g, rot r, dest d): {cos, signed_sin, partner, 0};
// forward: new[d] = cos*old[d] + signed_sin*old[partner]
__global__ void k_tbl(const int* __restrict__ gp, const float* __restrict__ ga,
                      const int* __restrict__ dp, const float* __restrict__ da,
                      const float* __restrict__ gch, const float* __restrict__ dch,
                      float4* __restrict__ tg, float4* __restrict__ td,
                      float* __restrict__ grch, float* __restrict__ drch) {
  const int t = blockIdx.x * 256 + threadIdx.x;
  if (t < NROT * (HIDDEN / 2)) {
    const int r = t >> 10, s = t & 1023;          // slot s over 1024 pairs
    const int grp = s >> 6;
    const int i = gp[r * HIDDEN + 2 * s], j = gp[r * HIDDEN + 2 * s + 1];
    const float a = ga[r * (HIDDEN / 2) + s];
    const float c = cosf(a), sn = sinf(a);
    tg[(grp * NROT + r) * 128 + i] = make_float4(c, -sn, __int_as_float(j), 0.f);
    tg[(grp * NROT + r) * 128 + j] = make_float4(c,  sn, __int_as_float(i), 0.f);
  }
  if (t < NROT * (INTERM / 2)) {
    const int r = t / (INTERM / 2), s = t - r * (INTERM / 2);
    const int grp = s >> 6;
    const int i = dp[r * INTERM + 2 * s], j = dp[r * INTERM + 2 * s + 1];
    const float a = da[r * (INTERM / 2) + s];
    const float c = cosf(a), sn = sinf(a);
    td[(grp * NROT + r) * 128 + i] = make_float4(c, -sn, __int_as_float(j), 0.f);
    td[(grp * NROT + r) * 128 + j] = make_float4(c,  sn, __int_as_float(i), 0.f);
  }
  if (t < HIDDEN) grch[t] = 1.0f / gch[t];
  if (t < INTERM) drch[t] = 1.0f / dch[t];
}

// helper: 4 forward rotation passes on (v0,v1) held across the wave (128-group)
// (bpermute variant, used by k_rotx / k_silu2)
#define FWD_ROT(tl, v0, v1)                                                     \
  _Pragma("unroll")                                                             \
  for (int r = 0; r < NROT; ++r) {                                              \
    const float4 e0 = tl[r * 128 + l];                                          \
    const float4 e1 = tl[r * 128 + 64 + l];                                     \
    const int p0 = __float_as_int(e0.z), p1 = __float_as_int(e1.z);             \
    const int a0 = (p0 & 63) << 2, a1 = (p1 & 63) << 2;                         \
    _Pragma("unroll")                                                           \
    for (int q = 0; q < 4; ++q) {                                               \
      const int x0 = __float_as_int(v0[q]), x1 = __float_as_int(v1[q]);         \
      const float lo0 = __int_as_float(__builtin_amdgcn_ds_bpermute(a0, x0));   \
      const float hi0 = __int_as_float(__builtin_amdgcn_ds_bpermute(a0, x1));   \
      const float lo1 = __int_as_float(__builtin_amdgcn_ds_bpermute(a1, x0));   \
      const float hi1 = __int_as_float(__builtin_amdgcn_ds_bpermute(a1, x1));   \
      const float op0 = (p0 & 64) ? hi0 : lo0;                                  \
      const float op1 = (p1 & 64) ? hi1 : lo1;                                  \
      {                                                                         \
        _Pragma("clang fp contract(off)")                                       \
        v0[q] = e0.x * v0[q] + e0.y * op0;                                      \
        v1[q] = e1.x * v1[q] + e1.y * op1;                                      \
      }                                                                         \
    }                                                                           \
  }

// ---------------- weight pseudo-quantize (forward only, outputs rotated q) ------
// v2: 8 rows/wave (2x amortization + 2x ILP through divides/butterfly), rotation
// partner fetch via per-wave LDS scratch: write [row][col], read [row][partner]
// at its FULL 0..127 index -> no lo/hi double-bpermute, no cmp+cndmask select.
// Same-wave DS ops execute in order (no barrier needed); compiler may-alias
// keeps write->read order. Arithmetic order/rounding UNCHANGED -> bitwise-
// identical output (absmax must stay exactly 0.01977539).
__global__ __launch_bounds__(256) void k_quant(
    const float* __restrict__ W, const float4* __restrict__ tbl,
    const float* __restrict__ ch, unsigned short* __restrict__ out, int In, int G) {
  __shared__ float4 tl[NROT * 128];
  __shared__ float rbuf[4][8 * 128];              // 16 KiB: per-wave rotation scratch
  const int wv = threadIdx.x >> 6, l = threadIdx.x & 63;
  const int g = blockIdx.x % G;
  const int rowblk = blockIdx.x / G;
  const int row0 = rowblk * 32 + wv * 8;
  const int colbase = g << 7;
  tl[threadIdx.x]       = tbl[(size_t)g * NROT * 128 + threadIdx.x];
  tl[256 + threadIdx.x] = tbl[(size_t)g * NROT * 128 + 256 + threadIdx.x];
  __syncthreads();
  const float c0 = ch[colbase + l], c1 = ch[colbase + 64 + l];
  float v0[8], v1[8];
#pragma unroll
  for (int q = 0; q < 8; ++q) {
#pragma clang fp contract(off)
    const float* Wr = W + (size_t)(row0 + q) * In + colbase;
    v0[q] = Wr[l] * c0;
    v1[q] = Wr[64 + l] * c1;
  }
  float* rb = rbuf[wv];
#pragma unroll
  for (int r = 0; r < NROT; ++r) {
    const float4 e0 = tl[r * 128 + l];
    const float4 e1 = tl[r * 128 + 64 + l];
    const int p0 = __float_as_int(e0.z), p1 = __float_as_int(e1.z);
#pragma unroll
    for (int q = 0; q < 8; ++q) {               // publish current values
      rb[q * 128 + l]      = v0[q];
      rb[q * 128 + 64 + l] = v1[q];
    }
#pragma unroll
    for (int q = 0; q < 8; ++q) {               // fetch partners (full-range idx)
      const float op0 = rb[q * 128 + p0];
      const float op1 = rb[q * 128 + p1];
      {
#pragma clang fp contract(off)
        v0[q] = e0.x * v0[q] + e0.y * op0;
        v1[q] = e1.x * v1[q] + e1.y * op1;
      }
    }
  }
  // fake quant per row; output stays in rotated space (math identical to v1)
#pragma unroll
  for (int q = 0; q < 8; ++q) {
    float mn = fminf(v0[q], v1[q]), mx = fmaxf(v0[q], v1[q]);
#pragma unroll
    for (int o = 32; o > 0; o >>= 1) {
      mn = fminf(mn, __shfl_xor(mn, o));
      mx = fmaxf(mx, __shfl_xor(mx, o));
    }
    {
#pragma clang fp contract(off)
      const float scale = fmaxf(mx - mn, 1e-5f) / 15.0f;
      const float zero = rintf(-mn / scale);
      const float q0 = fminf(fmaxf(rintf(v0[q] / scale) + zero, 0.0f), 15.0f);
      const float q1 = fminf(fmaxf(rintf(v1[q] / scale) + zero, 0.0f), 15.0f);
      v0[q] = (q0 - zero) * scale;
      v1[q] = (q1 - zero) * scale;
    }
  }
#pragma unroll
  for (int q = 0; q < 8; ++q) {
    unsigned short* Or = out + (size_t)(row0 + q) * In + colbase;
    Or[l]      = f2bf(v0[q]);
    Or[64 + l] = f2bf(v1[q]);
  }
}

// ---------------- x' = R(x / ch) -> bf16 ----------------
__global__ __launch_bounds__(256) void k_rotx(
    const float* __restrict__ X, const float* __restrict__ rch,
    const float4* __restrict__ tbl, unsigned short* __restrict__ out) {
  __shared__ float4 tl[NROT * 128];
  const int wv = threadIdx.x >> 6, l = threadIdx.x & 63;
  const int g = blockIdx.x % 16;                 // HIDDEN/128 groups
  const int rowblk = blockIdx.x / 16;
  const int row0 = rowblk * 16 + wv * 4;
  const int colbase = g << 7;
  tl[threadIdx.x]       = tbl[(size_t)g * NROT * 128 + threadIdx.x];
  tl[256 + threadIdx.x] = tbl[(size_t)g * NROT * 128 + 256 + threadIdx.x];
  __syncthreads();
  const float i0 = rch[colbase + l], i1 = rch[colbase + 64 + l];
  float v0[4], v1[4];
#pragma unroll
  for (int q = 0; q < 4; ++q) {
    const float* Xr = X + (size_t)(row0 + q) * HIDDEN + colbase;
    v0[q] = Xr[l] * i0;
    v1[q] = Xr[64 + l] * i1;
  }
  FWD_ROT(tl, v0, v1)
#pragma unroll
  for (int q = 0; q < 4; ++q) {
    unsigned short* Or = out + (size_t)(row0 + q) * HIDDEN + colbase;
    Or[l]      = f2bf(v0[q]);
    Or[64 + l] = f2bf(v1[q]);
  }
}

// ---------------- inter' = R_d( silu(gate)*up*wgt / ch_d ) -> bf16 ----------------
__global__ __launch_bounds__(256) void k_silu2(
    const float* __restrict__ h, const float* __restrict__ pw,
    const float* __restrict__ rch, const float4* __restrict__ tbl,
    unsigned short* __restrict__ out) {
  __shared__ float4 tl[NROT * 128];
  const int wv = threadIdx.x >> 6, l = threadIdx.x & 63;
  const int g = blockIdx.x % 6;                  // INTERM/128 groups
  const int rowblk = blockIdx.x / 6;
  const int row0 = rowblk * 16 + wv * 4;
  const int colbase = g << 7;
  tl[threadIdx.x]       = tbl[(size_t)g * NROT * 128 + threadIdx.x];
  tl[256 + threadIdx.x] = tbl[(size_t)g * NROT * 128 + 256 + threadIdx.x];
  __syncthreads();
  const float i0 = rch[colbase + l], i1 = rch[colbase + 64 + l];
  float v0[4], v1[4];
#pragma unroll
  for (int q = 0; q < 4; ++q) {
    const int row = row0 + q;
    const float wgt = pw[row];
    const float* hr = h + (size_t)row * 1536 + colbase;
    const float g0 = hr[l], g1 = hr[64 + l];
    const float u0 = hr[768 + l], u1 = hr[768 + 64 + l];
    v0[q] = g0 / (1.0f + expf(-g0)) * u0 * wgt * i0;
    v1[q] = g1 / (1.0f + expf(-g1)) * u1 * wgt * i1;
  }
  FWD_ROT(tl, v0, v1)
#pragma unroll
  for (int q = 0; q < 4; ++q) {
    unsigned short* Or = out + (size_t)(row0 + q) * INTERM + colbase;
    Or[l]      = f2bf(v0[q]);
    Or[64 + l] = f2bf(v1[q]);
  }
}

// ---------------- gate-up GEMM (MODE 0 only): C = A * B^T ----------------
// 256x256 tile, BK=64, 8 waves (2x4), 8-phase schedule, counted vmcnt(4),
// raw s_barrier pairs, setprio around MFMA, conflict-free both-sides swizzle.
template <int MODE>
__launch_bounds__(512, 2)
__global__ void k_gemm(const unsigned short* __restrict__ A,
                       const unsigned short* __restrict__ Bw,
                       float* __restrict__ C,
                       const int* __restrict__ pt,
                       const int* __restrict__ off,
                       const int* __restrict__ cnt,
                       const int* __restrict__ tmap,
                       const int* __restrict__ nv) {
  constexpr int K = MODE ? INTERM : HIDDEN;
  constexpr int N = MODE ? HIDDEN : 2 * INTERM;
  constexpr int XW = MODE ? 8 : 6;            // n-tiles of 256
  constexpr int NT = K / 64;                  // K-tiles

  const int hw  = blockIdx.x + XW * blockIdx.y;
  const int xcd = hw & 7;
  const int pos = hw >> 3;
  const int nvalid = nv[0];
  const int q8 = nvalid >> 3, r8 = nvalid & 7;
  const int rs = q8 + (xcd < r8 ? 1 : 0);
  const int y0 = xcd * q8 + (xcd < r8 ? xcd : r8);
  if (pos >= rs * XW) return;
  const int xg = pos % XW;
  const int yg = y0 + pos / XW;
  const int tm = tmap[yg];
  if (tm < 0) return;
  const int e = tm >> 16;
  const int m0 = (tm & 0xffff) << 8;
  const int count = cnt[e];
  const int seg = off[e];
  const int n0 = xg * 256;
  const unsigned short* Be = Bw + (size_t)e * N * K;

  __shared__ unsigned short lds[65536];       // 128 KiB

  const int tid = threadIdx.x;
  const int w = tid >> 6, l = tid & 63;
  const int wm = w >> 2, wn = w & 3;
  const int w512 = w * 512;

  // ---- stage source pointers (pre-swizzled chunk: c ^ ((row>>1)&3)) ----
  const int sr = tid >> 2;                              // stage row 0..127
  const int cs = (((tid & 3) ^ ((tid >> 3) & 3))) * 8;  // element offset of 16B chunk
  int pA0 = m0 + sr;        if (pA0 > count - 1) pA0 = count - 1;
  int pA1 = m0 + sr + 128;  if (pA1 > count - 1) pA1 = count - 1;
  size_t arow0, arow1;
  if (MODE == 0) { arow0 = (size_t)(pt[seg + pA0] >> 1); arow1 = (size_t)(pt[seg + pA1] >> 1); }
  else           { arow0 = (size_t)(seg + pA0); arow1 = (size_t)(seg + pA1); }
  const unsigned short* paS0 = A + arow0 * K + cs;
  const unsigned short* paS1 = A + arow1 * K + cs;
  const unsigned short* pbS0 = Be + (size_t)(n0 + sr) * K + cs;
  const unsigned short* pbS1 = Be + (size_t)(n0 + sr + 128) * K + cs;

  // ---- fragment read offsets (same XOR: q ^ ((row>>1)&3), row%16 = l&15) ----
  const int cswz  = ((l >> 4) ^ (((l & 15) >> 1) & 3)) * 8;
  const int abase = (wm * 128 + (l & 15)) * 32 + cswz;            // within A ksub half
  const int bbase = (wn * 64  + (l & 15)) * 32 + cswz + 16384;    // +B offset folded

  f32x4 acc[8][4];
#pragma unroll
  for (int i = 0; i < 8; ++i)
#pragma unroll
    for (int j = 0; j < 4; ++j) acc[i][j] = (f32x4)0.0f;

  // layout (ushort units): buf*32768 + {A:0,B:16384} + ksub*8192 + row*32 + chunk*8
#define STG_A(dst, koff) do { \
    async16(paS0 + (koff), &lds[(dst) + w512]); \
    async16(paS1 + (koff), &lds[(dst) + 4096 + w512]); } while (0)
#define STG_B(dst, koff) do { \
    async16(pbS0 + (koff), &lds[(dst) + w512]); \
    async16(pbS1 + (koff), &lds[(dst) + 4096 + w512]); } while (0)

  // prologue: t0 fully + t1 kh0   (12 vmem instr; newest 4 = t1 kh0 stay in flight)
  STG_A(0,     0);  STG_B(16384,       0);
  STG_A(8192,  32); STG_B(16384+8192,  32);
  STG_A(32768, 64); STG_B(32768+16384, 64);
  asm volatile("s_waitcnt vmcnt(4)" ::: "memory");
  __builtin_amdgcn_s_barrier();

  for (int t = 0; t < NT; ++t) {
    const int base = (t & 1) << 15;            // 0 / 32768
    const int alt  = base ^ 32768;
    const int k1 = (t + 1) * 64, k2 = (t + 2) * 64;
    bf16x8 a[4], bq[4];

    // ---------------- phase 1: ksub0, m-half0 (+B ksub0) ----------------
#pragma unroll
    for (int ii = 0; ii < 4; ++ii) a[ii]  = *(const bf16x8*)&lds[base + abase + ii * 512];
#pragma unroll
    for (int j = 0; j < 4; ++j)    bq[j]  = *(const bf16x8*)&lds[base + bbase + j * 512];
    if (t + 1 < NT) STG_A(alt + 8192, k1 + 32);            // A-kh1(t+1) -> idle buf
    __builtin_amdgcn_s_barrier();
    asm volatile("s_waitcnt lgkmcnt(0)" ::: "memory");
    __builtin_amdgcn_sched_barrier(0);
    __builtin_amdgcn_s_setprio(1);
#pragma unroll
    for (int ii = 0; ii < 4; ++ii)
#pragma unroll
      for (int j = 0; j < 4; ++j)
        acc[ii][j] = __builtin_amdgcn_mfma_f32_16x16x32_bf16(a[ii], bq[j], acc[ii][j], 0, 0, 0);
    __builtin_amdgcn_s_setprio(0);
    __builtin_amdgcn_s_barrier();

    // ---------------- phase 2: ksub0, m-half1 ----------------
#pragma unroll
    for (int ii = 0; ii < 4; ++ii) a[ii] = *(const bf16x8*)&lds[base + abase + (4 + ii) * 512];
    if (t + 1 < NT) STG_B(alt + 16384 + 8192, k1 + 32);    // B-kh1(t+1) -> idle buf
    __builtin_amdgcn_s_barrier();
    asm volatile("s_waitcnt lgkmcnt(0)" ::: "memory");
    __builtin_amdgcn_sched_barrier(0);
    __builtin_amdgcn_s_setprio(1);
#pragma unroll
    for (int ii = 0; ii < 4; ++ii)
#pragma unroll
      for (int j = 0; j < 4; ++j)
        acc[4 + ii][j] = __builtin_amdgcn_mfma_f32_16x16x32_bf16(a[ii], bq[j], acc[4 + ii][j], 0, 0, 0);
    __builtin_amdgcn_s_setprio(0);
    __builtin_amdgcn_s_barrier();

    // ---------------- phase 3: ksub1, m-half0 (+B ksub1) ----------------
#pragma unroll
    for (int ii = 0; ii < 4; ++ii) a[ii] = *(const bf16x8*)&lds[base + 8192 + abase + ii * 512];
#pragma unroll
    for (int j = 0; j < 4; ++j)    bq[j] = *(const bf16x8*)&lds[base + 8192 + bbase + j * 512];
    if (t + 2 < NT) STG_A(base, k2);                       // A-kh0(t+2) -> cur buf (kh0 free)
    __builtin_amdgcn_s_barrier();
    asm volatile("s_waitcnt lgkmcnt(0)" ::: "memory");
    __builtin_amdgcn_sched_barrier(0);
    __builtin_amdgcn_s_setprio(1);
#pragma unroll
    for (int ii = 0; ii < 4; ++ii)
#pragma unroll
      for (int j = 0; j < 4; ++j)
        acc[ii][j] = __builtin_amdgcn_mfma_f32_16x16x32_bf16(a[ii], bq[j], acc[ii][j], 0, 0, 0);
    __builtin_amdgcn_s_setprio(0);
    __builtin_amdgcn_s_barrier();

    // ---------------- phase 4: ksub1, m-half1 ----------------
#pragma unroll
    for (int ii = 0; ii < 4; ++ii) a[ii] = *(const bf16x8*)&lds[base + 8192 + abase + (4 + ii) * 512];
    if (t + 2 < NT) STG_B(base + 16384, k2);               // B-kh0(t+2) -> cur buf
    __builtin_amdgcn_s_barrier();
    asm volatile("s_waitcnt lgkmcnt(0)" ::: "memory");
    __builtin_amdgcn_sched_barrier(0);
    __builtin_amdgcn_s_setprio(1);
#pragma unroll
    for (int ii = 0; ii < 4; ++ii)
#pragma unroll
      for (int j = 0; j < 4; ++j)
        acc[4 + ii][j] = __builtin_amdgcn_mfma_f32_16x16x32_bf16(a[ii], bq[j], acc[4 + ii][j], 0, 0, 0);
    __builtin_amdgcn_s_setprio(0);
    if (t + 1 < NT) {                       // tile boundary: counted vmcnt (T4)
      if (t + 1 == NT - 1) asm volatile("s_waitcnt vmcnt(0)" ::: "memory");
      else                 asm volatile("s_waitcnt vmcnt(4)" ::: "memory");
    }
    __builtin_amdgcn_s_barrier();
  }
#undef STG_A
#undef STG_B

  // ---------------- epilogue ----------------
  const int mb = wm * 128 + (l >> 4) * 4;
  const int nb = n0 + wn * 64 + (l & 15);
#pragma unroll
  for (int i = 0; i < 8; ++i) {
#pragma unroll
    for (int j = 0; j < 4; ++j) {
#pragma unroll
      for (int r = 0; r < 4; ++r) {
        const int mm = m0 + mb + i * 16 + r;
        if (mm < count) {
          const int nn = nb + j * 16;
          if (MODE == 0) {
            C[(size_t)(seg + mm) * N + nn] = acc[i][j][r];
          } else {
            C[(size_t)pt[seg + mm] * N + nn] = acc[i][j][r];
          }
        }
      }
    }
  }
}

// ---------------- down GEMM: 256x128 tile, BK=32, 2 blocks/CU, 2-phase ----------
__launch_bounds__(512, 4)
__global__ void k_gemm1(const unsigned short* __restrict__ A,
                        const unsigned short* __restrict__ Bw,
                        float* __restrict__ C,
                        const int* __restrict__ pt,
                        const int* __restrict__ off,
                        const int* __restrict__ cnt,
                        const int* __restrict__ tmap,
                        const int* __restrict__ nv) {
  constexpr int K = INTERM;                 // 768
  constexpr int N = HIDDEN;                 // 2048
  constexpr int XW = 16;                    // n-tiles of 128
  constexpr int NT = K / 32;                // 24 K-tiles

  const int hw  = blockIdx.x + XW * blockIdx.y;
  const int xcd = hw & 7;
  const int pos = hw >> 3;
  const int nvalid = nv[0];
  const int q8 = nvalid >> 3, r8 = nvalid & 7;
  const int rs = q8 + (xcd < r8 ? 1 : 0);
  const int y0 = xcd * q8 + (xcd < r8 ? xcd : r8);
  if (pos >= rs * XW) return;
  const int xg = pos % XW;
  const int yg = y0 + pos / XW;
  const int tm = tmap[yg];
  if (tm < 0) return;
  const int e = tm >> 16;
  const int m0 = (tm & 0xffff) << 8;
  const int count = cnt[e];
  const int seg = off[e];
  const int n0 = xg * 128;
  const unsigned short* Be = Bw + (size_t)e * N * K;

  __shared__ unsigned short lds[24576];     // 48 KiB: [2][A:8192 | B:4096] ushort

  const int tid = threadIdx.x;
  const int w = tid >> 6, l = tid & 63;
  const int wm = w >> 1, wn = w & 1;        // 4m x 2n waves, wave-tile 64x64
  const int w512 = w * 512;

  // stage: A rows sr, sr+128 (2 chunks/thread), B row sr (1 chunk/thread)
  const int sr = tid >> 2;
  const int cs = ((tid & 3) ^ ((tid >> 3) & 3)) * 8;   // pre-swizzled source chunk
  int pA0 = m0 + sr;        if (pA0 > count - 1) pA0 = count - 1;
  int pA1 = m0 + sr + 128;  if (pA1 > count - 1) pA1 = count - 1;
  const unsigned short* paS0 = A + (size_t)(seg + pA0) * K + cs;
  const unsigned short* paS1 = A + (size_t)(seg + pA1) * K + cs;
  const unsigned short* pbS0 = Be + (size_t)(n0 + sr) * K + cs;

  // fragment reads (same XOR involution on the read side)
  const int cswz  = ((l >> 4) ^ (((l & 15) >> 1) & 3)) * 8;
  const int abase = (wm * 64 + (l & 15)) * 32 + cswz;
  const int bbase = 8192 + (wn * 64 + (l & 15)) * 32 + cswz;

  f32x4 acc[4][4];
#pragma unroll
  for (int i = 0; i < 4; ++i)
#pragma unroll
    for (int j = 0; j < 4; ++j) acc[i][j] = (f32x4)0.0f;

  // layout (ushort): buf*12288 + {A: row*32 (rows 0..255), B: 8192 + row*32}
#define STG1(b, koff) do {                                   \
    async16(paS0 + (koff), &lds[(b) * 12288 + w512]);        \
    async16(paS1 + (koff), &lds[(b) * 12288 + 4096 + w512]); \
    async16(pbS0 + (koff), &lds[(b) * 12288 + 8192 + w512]); \
  } while (0)

  STG1(0, 0);                               // tile 0
  int buf = 0;
  for (int t = 0; t < NT; ++t) {
    __syncthreads();                        // vmcnt(0)+lgkmcnt(0)+barrier: tile t ready
    if (t + 1 < NT) STG1(buf ^ 1, (t + 1) * 32);
    const int lb = buf * 12288;
    bf16x8 a[4], bq[4];
#pragma unroll
    for (int i = 0; i < 4; ++i) a[i]  = *(const bf16x8*)&lds[lb + abase + i * 512];
#pragma unroll
    for (int j = 0; j < 4; ++j) bq[j] = *(const bf16x8*)&lds[lb + bbase + j * 512];
#pragma unroll
    for (int i = 0; i < 4; ++i)
#pragma unroll
      for (int j = 0; j < 4; ++j)
        acc[i][j] = __builtin_amdgcn_mfma_f32_16x16x32_bf16(a[i], bq[j], acc[i][j], 0, 0, 0);
    buf ^= 1;
  }
#undef STG1

  const int mb = wm * 64 + (l >> 4) * 4;
  const int nb = n0 + wn * 64 + (l & 15);
#pragma unroll
  for (int i = 0; i < 4; ++i) {
#pragma unroll
    for (int j = 0; j < 4; ++j) {
#pragma unroll
      for (int r = 0; r < 4; ++r) {
        const int mm = m0 + mb + i * 16 + r;
        if (mm < count) {
          C[(size_t)pt[seg + mm] * N + nb + j * 16] = acc[i][j][r];
        }
      }
    }
  }
}

// ---------------- out[t] = ybuf[2t] + ybuf[2t+1] ----------------
__global__ __launch_bounds__(256) void k_combine(const float4* __restrict__ y,
                                                 float4* __restrict__ out) {
  const int t = blockIdx.x;                       // token
  const float4* y0 = y + (size_t)(2 * t) * (HIDDEN / 4);
  const float4* y1 = y + (size_t)(2 * t + 1) * (HIDDEN / 4);
  float4* o = out + (size_t)t * (HIDDEN / 4);
#pragma unroll
  for (int q = 0; q < 2; ++q) {
    const int c = threadIdx.x + q * 256;          // 512 float4 per token
    const float4 a = y0[c], b = y1[c];
    o[c] = make_float4(a.x + b.x, a.y + b.y, a.z + b.z, a.w + b.w);
  }
}

// ---------------- launch ----------------
extern "C" void kernel_launch(void* const* d_in, const int* in_sizes, int n_in,
                              void* d_out, int out_size, void* d_ws, size_t ws_size,
                              hipStream_t stream) {
  const float* hs  = (const float*)d_in[0];
  const int*   tki = (const int*)d_in[1];
  const float* tkw = (const float*)d_in[2];
  const float* guw = (const float*)d_in[3];
  const float* dww = (const float*)d_in[4];
  const int*   gupr= (const int*)d_in[5];
  const float* gua = (const float*)d_in[6];
  const int*   dwp = (const int*)d_in[7];
  const float* dwa = (const float*)d_in[8];
  const float* gus = (const float*)d_in[9];
  const float* dwsc= (const float*)d_in[10];
  float* out = (float*)d_out;
  char* ws = (char*)d_ws;

  unsigned short* gup_bf = (unsigned short*)(ws + 0);          //  50,331,648 B
  unsigned short* dwn_bf = (unsigned short*)(ws + 50331648);   //  25,165,824 B
  unsigned short* x_bf   = (unsigned short*)(ws + 75497472);   //  16,777,216 B
  float*          hbuf   = (float*)(ws + 92274688);            //  50,331,648 B
  unsigned short* interb = (unsigned short*)(ws + 142606336);  //  12,582,912 B
  // ybuf (8192 x 2048 f32 = 67,108,864 B) reuses x_bf + hbuf (both dead after k_silu2)
  float*          ybuf   = (float*)(ws + 75497472);
  int*            pt     = (int*)(ws + 155189248);             //  32,768 B
  float*          pw     = (float*)(ws + 155222016);           //  32,768 B
  int*            cnt    = (int*)(ws + 155254784);             //  cnt/off/cur/tmap/nv (<4 KiB)
  int*            off    = cnt + 8;
  int*            cur    = cnt + 16;
  int*            tmap   = cnt + 24;
  int*            nv     = cnt + 120;
  float4*         tg     = (float4*)(ws + 155258880);          // 131,072 B (16 grp)
  float4*         td     = (float4*)(ws + 155389952);          //  49,152 B (6 grp)
  float*          grch   = (float*)(ws + 155439104);           //   8,192 B
  float*          drch   = (float*)(ws + 155447296);           //   3,072 B

  (void)hipMemsetAsync(cnt, 0, 32, stream);

  k_hist<<<32, 256, 0, stream>>>(tki, cnt);
  k_scan<<<1, 64, 0, stream>>>(cnt, off, cur, tmap, nv);
  k_scatter<<<32, 256, 0, stream>>>(tki, tkw, off, cur, pt, pw);
  k_tbl<<<16, 256, 0, stream>>>(gupr, gua, dwp, dwa, gus, dwsc, tg, td, grch, drch);
  k_rotx<<<4096, 256, 0, stream>>>(hs, grch, tg, x_bf);
  k_quant<<<6144, 256, 0, stream>>>(guw, tg, gus, gup_bf, HIDDEN, 16);
  k_quant<<<3072, 256, 0, stream>>>(dww, td, dwsc, dwn_bf, INTERM, 6);
  k_gemm<0><<<dim3(6, MAXT), 512, 0, stream>>>(x_bf, gup_bf, hbuf, pt, off, cnt, tmap, nv);
  k_silu2<<<3072, 256, 0, stream>>>(hbuf, pw, drch, td, interb);
  k_gemm1<<<dim3(16, MAXT), 512, 0, stream>>>(interb, dwn_bf, ybuf, pt, off, cnt, tmap, nv);
  k_combine<<<T_TOKENS, 256, 0, stream>>>((const float4*)ybuf, (float4*)out);
}